// Round 18
// baseline (123.076 us; speedup 1.0000x reference)
//
#include <hip/hip_runtime.h>
#include <stdint.h>

typedef __attribute__((ext_vector_type(8))) __bf16 bf16x8;
typedef __attribute__((ext_vector_type(4))) __bf16 bf16x4;
typedef __attribute__((ext_vector_type(4))) float f32x4;
typedef __attribute__((ext_vector_type(4))) unsigned int u32x4;

#define SEQ 2048
#define LOG2E 1.4426950408889634f

// ---------- ws layout (bytes) ----------
#define OFF_HS2   0ull               // bf16 [8192][1024]
#define OFF_AO    8388608ull         // bf16 [8192][512] (overlay; hs2 dead after QKV GEMM)
#define OFF_WQKV2 16777216ull        // bf16 [1536][1536]
#define OFF_WO    21495808ull        // bf16 [512][512]
#define OFF_QH    22020096ull        // bf16 [32][2048][64]
#define OFF_QL    30408704ull
#define OFF_K     38797312ull
#define OFF_VT    47185920ull        // bf16 [32][64][2048] (GEMM epilogue, s-permuted)
#define OFF_BIAS  55574528ull        // f32 [8][4096] (log2e-scaled)

__device__ __forceinline__ int swz(int row) { return ((row & 7) << 4) ^ ((row & 8) << 1); }

__device__ __forceinline__ void gl_lds16(const void* g, void* l) {
  __builtin_amdgcn_global_load_lds(
      (__attribute__((address_space(1))) void*)(uintptr_t)g,
      (__attribute__((address_space(3))) void*)(uint32_t)(uintptr_t)l, 16, 0, 0);
}

__device__ __forceinline__ float fast_exp2(float x) { return __builtin_amdgcn_exp2f(x); }

// ---------- prep: weights (z<3 split QKV / z==3 Wo+bias) and hs cast (z>=4) ----------
__global__ void k_prep(const float* __restrict__ hs,
                       const float* __restrict__ Wq, const float* __restrict__ Wk,
                       const float* __restrict__ Wv, const float* __restrict__ Wo,
                       const float* __restrict__ rel_bias,
                       __bf16* __restrict__ hs2, __bf16* __restrict__ w2,
                       __bf16* __restrict__ wo_t, float* __restrict__ bias_tab) {
  int z = blockIdx.z;
  if (z >= 4) {
    int cid = (z - 4) * 64 + blockIdx.y * 8 + blockIdx.x;
    int gid = cid * 256 + threadIdx.x;
    int row = gid >> 6, c8 = (gid & 63) * 8;
    const float* p = hs + (size_t)row * 512 + c8;
    float4 a = *(const float4*)p, b = *(const float4*)(p + 4);
    float v[8] = {a.x, a.y, a.z, a.w, b.x, b.y, b.z, b.w};
    bf16x8 hi, lo;
#pragma unroll
    for (int j = 0; j < 8; ++j) {
      __bf16 h = (__bf16)v[j];
      hi[j] = h;
      lo[j] = (__bf16)(v[j] - (float)h);
    }
    *(bf16x8*)(hs2 + (size_t)row * 1024 + c8) = hi;
    *(bf16x8*)(hs2 + (size_t)row * 1024 + 512 + c8) = lo;
    return;
  }
  __shared__ float tile[64][65];
  const float* W = (z == 0) ? Wq : (z == 1) ? Wk : (z == 2) ? Wv : Wo;
  int k0 = blockIdx.y * 64, n0 = blockIdx.x * 64;
  int tx = threadIdx.x & 63, ty = threadIdx.x >> 6;
  for (int r = ty; r < 64; r += 4) tile[r][tx] = W[(size_t)(k0 + r) * 512 + n0 + tx];
  __syncthreads();
  if (z < 3) {
    float scale = (z == 0) ? LOG2E : 1.0f;
    for (int r = ty; r < 64; r += 4) {
      float v = tile[tx][r] * scale;
      __bf16 h = (__bf16)v;
      __bf16 lo = (__bf16)(v - (float)h);
      __bf16* dst = w2 + (size_t)(z * 512 + n0 + r) * 1536;
      dst[k0 + tx] = h;
      dst[512 + k0 + tx] = h;
      dst[1024 + k0 + tx] = lo;
    }
  } else {
    for (int r = ty; r < 64; r += 4)
      wo_t[(size_t)(n0 + r) * 512 + k0 + tx] = (__bf16)tile[tx][r];
    int blk = blockIdx.y * 8 + blockIdx.x;
#pragma unroll
    for (int e = 0; e < 2; ++e) {
      int idx = blk * 512 + e * 256 + threadIdx.x;
      int h = idx >> 12, dIdx = idx & 4095;
      float v = 0.f;
      if (dIdx < 4095) {
        int d = dIdx - 2047;
        int rp = d < 0 ? -d : d;
        int bp;
        if (rp < 8) bp = rp;
        else bp = 8 + (rp >= 12) + (rp >= 16) + (rp >= 23) + (rp >= 32) + (rp >= 46) + (rp >= 64) + (rp >= 91);
        v = rel_bias[((d > 0 ? 16 : 0) + bp) * 8 + h] * LOG2E;
      }
      bias_tab[idx] = v;
    }
  }
}

// ---------- GEMM; MODE 0: class-ordered grid (Q 48, K 32, V 16 K-steps), V writes vt ----------
template <int MODE, int KSTEPS, int LDA, int LDB>
__global__ __launch_bounds__(256) void k_gemm(const __bf16* __restrict__ A,
                                              const __bf16* __restrict__ Bt,
                                              __bf16* __restrict__ qh, __bf16* __restrict__ ql,
                                              __bf16* __restrict__ ko, __bf16* __restrict__ vt,
                                              float* __restrict__ fo) {
  __shared__ __align__(16) __bf16 As[2][128 * 32];
  __shared__ __align__(16) __bf16 Bs[2][128 * 32];
  int tid = threadIdx.x, w = tid >> 6, l = tid & 63;
  int lr = l & 15, lh = l >> 4;
  int m0, n0, ksteps;
  if (MODE == 0) {
    int flat = blockIdx.x;                      // 768 blocks, heavy-Q class first
    int C = flat >> 8, local = flat & 255;
    int local2 = (local & 7) * 32 + (local >> 3);
    m0 = (local2 >> 2) * 128;
    n0 = ((C << 2) | (local2 & 3)) * 128;
    ksteps = (C == 0) ? 48 : (C == 1) ? 32 : 16;
  } else {
    int nwg = gridDim.x * gridDim.y;
    int flat = blockIdx.y * gridDim.x + blockIdx.x;
    int flat2 = (flat & 7) * (nwg >> 3) + (flat >> 3);
    m0 = (flat2 / gridDim.x) * 128;
    n0 = (flat2 % gridDim.x) * 128;
    ksteps = KSTEPS;
  }
  int wm = (w >> 1) * 64, wn = (w & 1) * 64;
  f32x4 zero4 = {0.f, 0.f, 0.f, 0.f};
  f32x4 acc[4][4];
#pragma unroll
  for (int i = 0; i < 4; ++i)
#pragma unroll
    for (int j = 0; j < 4; ++j) acc[i][j] = zero4;

  auto stage = [&](int kt, int buf) {
    int ka = (MODE == 0 && kt >= 32) ? kt - 32 : kt;
#pragma unroll
    for (int c = 0; c < 2; ++c) {
      int i = c * 256 + w * 64 + l;
      int row = i >> 2, cc = i & 3;
      gl_lds16(A + (size_t)(m0 + row) * LDA + ka * 32 + cc * 8,
               (char*)&As[buf][0] + (c * 256 + w * 64) * 16);
      gl_lds16(Bt + (size_t)(n0 + row) * LDB + kt * 32 + cc * 8,
               (char*)&Bs[buf][0] + (c * 256 + w * 64) * 16);
    }
  };

  stage(0, 0);
  __syncthreads();
#pragma unroll 2
  for (int kt = 0; kt < ksteps; ++kt) {
    int cur = kt & 1;
    if (kt + 1 < ksteps) stage(kt + 1, cur ^ 1);
    bf16x8 af[4], bfr[4];
#pragma unroll
    for (int mi = 0; mi < 4; ++mi)
      af[mi] = *(const bf16x8*)&As[cur][(wm + mi * 16 + lr) * 32 + lh * 8];
#pragma unroll
    for (int ni = 0; ni < 4; ++ni)
      bfr[ni] = *(const bf16x8*)&Bs[cur][(wn + ni * 16 + lr) * 32 + lh * 8];
#pragma unroll
    for (int mi = 0; mi < 4; ++mi)
#pragma unroll
      for (int ni = 0; ni < 4; ++ni)
        acc[mi][ni] = __builtin_amdgcn_mfma_f32_16x16x32_bf16(af[mi], bfr[ni], acc[mi][ni], 0, 0, 0);
    __syncthreads();
  }

  if (MODE == 0 && n0 >= 1024) {
    // V epilogue: write transposed + s-permuted directly into vt[bh][dh][s']
#pragma unroll
    for (int mi = 0; mi < 4; ++mi)
#pragma unroll
      for (int ni = 0; ni < 4; ++ni) {
        int m = m0 + wm + mi * 16 + lh * 4;
        int n = n0 + wn + ni * 16 + lr;
        int c9 = n & 511, hh = c9 >> 6, dh = c9 & 63;
        int b = m >> 11, s = m & 2047;
        int loc = s & 63;
        int pp = ((loc >> 5) << 5) | (((loc >> 2) & 3) << 3) | (((loc >> 4) & 1) << 2);
        bf16x4 o;
#pragma unroll
        for (int r = 0; r < 4; ++r) o[r] = (__bf16)acc[mi][ni][r];
        *(bf16x4*)&vt[((size_t)(b * 8 + hh) * 64 + dh) * 2048 + (s & ~63) + pp] = o;
      }
    return;
  }

#pragma unroll
  for (int mi = 0; mi < 4; ++mi)
#pragma unroll
    for (int ni = 0; ni < 4; ++ni)
#pragma unroll
      for (int r = 0; r < 4; ++r) {
        int m = m0 + wm + mi * 16 + lh * 4 + r;
        int n = n0 + wn + ni * 16 + lr;
        float vv = acc[mi][ni][r];
        if (MODE == 0) {
          int which = n >> 9, c9 = n & 511, hh = c9 >> 6, dh = c9 & 63;
          int b = m >> 11, s = m & 2047;
          size_t o = (size_t)((b * 8 + hh) * 2048 + s) * 64 + dh;
          if (which == 0) {
            __bf16 hv = (__bf16)vv;
            qh[o] = hv;
            ql[o] = (__bf16)(vv - (float)hv);
          } else {
            ko[o] = (__bf16)vv;
          }
        } else {
          fo[(size_t)m * 512 + n] = vv;
        }
      }
}

// ---------- flash attention: swapped QK^T, bias-as-C, register P, 4-buffer KV ----------
__global__ __launch_bounds__(512) void k_attn(const __bf16* __restrict__ qhp,
                                              const __bf16* __restrict__ qlp,
                                              const __bf16* __restrict__ k,
                                              const __bf16* __restrict__ vt,
                                              const float* __restrict__ bias_tab,
                                              __bf16* __restrict__ ao) {
  __shared__ __align__(16) __bf16 Ks[4][64 * 64];
  __shared__ __align__(16) __bf16 Vs[4][64 * 64];
  __shared__ float bias_s[2176];
  int tid = threadIdx.x, w = tid >> 6, l = tid & 63;
  int lr = l & 15, lh = l >> 4;
  int d = blockIdx.x;
  int bh = (d & 7) + ((d >> 3) & 3) * 8;
  int q0 = (d >> 5) * 128;
  int h = bh & 7, b = bh >> 3;
  const char* kbase = (const char*)(k + (size_t)bh * SEQ * 64);
  const char* vbase = (const char*)(vt + (size_t)bh * 64 * SEQ);

  float bR = bias_tab[h * 4096 + 2047 + 200];
  float bL = bias_tab[h * 4096 + 2047 - 200];

  for (int j = tid; j < 2176; j += 512)
    bias_s[j] = bias_tab[h * 4096 + (1920 - q0) + j];

  auto stageKV = [&](int kt, int buf) {
    const char* kb = kbase + (size_t)kt * 64 * 128;
    const char* vb = vbase + (size_t)kt * 128;
    int row = tid >> 3, colb = (tid & 7) * 16;
    gl_lds16(kb + row * 128 + (colb ^ swz(row)), (char*)&Ks[buf][0] + tid * 16);
    gl_lds16(vb + (size_t)row * 4096 + (colb ^ swz(row)), (char*)&Vs[buf][0] + tid * 16);
  };

  // Q fragments straight from global
  bf16x8 qfh[2], qfl[2];
  int qrow = w * 16 + lr;
  {
    const __bf16* qg = qhp + ((size_t)bh * SEQ + q0 + qrow) * 64;
    qfh[0] = *(const bf16x8*)(qg + lh * 8);
    qfh[1] = *(const bf16x8*)(qg + 32 + lh * 8);
    const __bf16* qg2 = qlp + ((size_t)bh * SEQ + q0 + qrow) * 64;
    qfl[0] = *(const bf16x8*)(qg2 + lh * 8);
    qfl[1] = *(const bf16x8*)(qg2 + 32 + lh * 8);
  }

  float m_run = -1e30f, l_run = 0.f;
  f32x4 zero4 = {0.f, 0.f, 0.f, 0.f};
  f32x4 oacc[4];
#pragma unroll
  for (int i = 0; i < 4; ++i) oacc[i] = zero4;

  auto compute = [&](int kt, int buf) {
    // far/near classification + bias C-init (bias folds into the MFMA accumulate)
    int dmin = kt * 64 - q0 - 127, dmax = kt * 64 + 63 - q0;
    bool far = (dmin >= 91) || (dmax <= -91);
    float cb = far ? ((dmin >= 91) ? bR : bL) : 0.f;
    f32x4 cinit[4];
    if (far) {
#pragma unroll
      for (int t = 0; t < 4; ++t) cinit[t] = zero4;
    } else {
      int jb = kt * 64 + lh * 4 + 127 - (w * 16 + lr);
#pragma unroll
      for (int t = 0; t < 4; ++t)
#pragma unroll
        for (int r = 0; r < 4; ++r) cinit[t][r] = bias_s[jb + t * 16 + r];
    }
    const char* kb = (const char*)&Ks[buf][0];
    f32x4 sacc[4];
    __builtin_amdgcn_s_setprio(1);
#pragma unroll
    for (int t = 0; t < 4; ++t) {
      int row = t * 16 + lr;
      bf16x8 b0 = *(const bf16x8*)(kb + row * 128 + ((lh * 16) ^ swz(row)));
      bf16x8 b1 = *(const bf16x8*)(kb + row * 128 + ((64 + lh * 16) ^ swz(row)));
      f32x4 z = cinit[t];
      z = __builtin_amdgcn_mfma_f32_16x16x32_bf16(b0, qfh[0], z, 0, 0, 0);
      z = __builtin_amdgcn_mfma_f32_16x16x32_bf16(b1, qfh[1], z, 0, 0, 0);
      z = __builtin_amdgcn_mfma_f32_16x16x32_bf16(b0, qfl[0], z, 0, 0, 0);
      z = __builtin_amdgcn_mfma_f32_16x16x32_bf16(b1, qfl[1], z, 0, 0, 0);
      sacc[t] = z;
    }
    __builtin_amdgcn_s_setprio(0);
    // tree max over the 16 S values (short dep chain; clang can fuse v_max3)
    float mA = fmaxf(fmaxf(sacc[0][0], sacc[0][1]), fmaxf(sacc[0][2], sacc[0][3]));
    float mB = fmaxf(fmaxf(sacc[1][0], sacc[1][1]), fmaxf(sacc[1][2], sacc[1][3]));
    float mC = fmaxf(fmaxf(sacc[2][0], sacc[2][1]), fmaxf(sacc[2][2], sacc[2][3]));
    float mD = fmaxf(fmaxf(sacc[3][0], sacc[3][1]), fmaxf(sacc[3][2], sacc[3][3]));
    float mx = fmaxf(fmaxf(mA, mB), fmaxf(mC, mD));
    float me = m_run - cb;
    if (!__all(mx <= me + 11.5f)) {
      mx = fmaxf(mx, __shfl_xor(mx, 16));
      mx = fmaxf(mx, __shfl_xor(mx, 32));
      float men = fmaxf(me, mx);
      float sc = fast_exp2(me - men);
      m_run = men + cb;
      me = men;
      l_run *= sc;
#pragma unroll
      for (int r = 0; r < 4; ++r) {
        float scr = __shfl(sc, lh * 4 + r);
#pragma unroll
        for (int ni = 0; ni < 4; ++ni) oacc[ni][r] *= scr;
      }
    }
    float p[4][4];
    float rt[4];
#pragma unroll
    for (int t = 0; t < 4; ++t) {
#pragma unroll
      for (int r = 0; r < 4; ++r) p[t][r] = fast_exp2(sacc[t][r] - me);
      rt[t] = (p[t][0] + p[t][1]) + (p[t][2] + p[t][3]);
    }
    l_run += (rt[0] + rt[1]) + (rt[2] + rt[3]);
    uint32_t pk[4][2];
#pragma unroll
    for (int t = 0; t < 4; ++t) {
      asm("v_cvt_pk_bf16_f32 %0, %1, %2" : "=v"(pk[t][0]) : "v"(p[t][0]), "v"(p[t][1]));
      asm("v_cvt_pk_bf16_f32 %0, %1, %2" : "=v"(pk[t][1]) : "v"(p[t][2]), "v"(p[t][3]));
    }
    u32x4 A0 = {pk[0][0], pk[0][1], pk[1][0], pk[1][1]};
    u32x4 A1 = {pk[2][0], pk[2][1], pk[3][0], pk[3][1]};
    bf16x8 pa0 = __builtin_bit_cast(bf16x8, A0);
    bf16x8 pa1 = __builtin_bit_cast(bf16x8, A1);
    const char* vbr = (const char*)&Vs[buf][0];
    __builtin_amdgcn_s_setprio(1);
#pragma unroll
    for (int ni = 0; ni < 4; ++ni) {
      int vrow = ni * 16 + lr;
      bf16x8 v0 = *(const bf16x8*)(vbr + vrow * 128 + ((lh * 16) ^ swz(vrow)));
      bf16x8 v1 = *(const bf16x8*)(vbr + vrow * 128 + ((64 + lh * 16) ^ swz(vrow)));
      oacc[ni] = __builtin_amdgcn_mfma_f32_16x16x32_bf16(pa0, v0, oacc[ni], 0, 0, 0);
      oacc[ni] = __builtin_amdgcn_mfma_f32_16x16x32_bf16(pa1, v1, oacc[ni], 0, 0, 0);
    }
    __builtin_amdgcn_s_setprio(0);
  };

  // 4-buffer pipeline: one barrier per 2 kt; unroll 2 -> all buffer indices static
  stageKV(0, 0);
  stageKV(1, 1);
  __syncthreads();
#pragma unroll 2
  for (int kp = 0; kp < 16; ++kp) {
    int rb_ = (kp & 1) * 2;
    if (kp < 15) {
      stageKV(2 * kp + 2, rb_ ^ 2);
      stageKV(2 * kp + 3, (rb_ ^ 2) + 1);
    }
    compute(2 * kp, rb_);
    compute(2 * kp + 1, rb_ + 1);
    __syncthreads();
  }

  // one-time class reduce of per-lane l partials
  l_run += __shfl_xor(l_run, 16);
  l_run += __shfl_xor(l_run, 32);

#pragma unroll
  for (int r = 0; r < 4; ++r) {
    float linv = 1.0f / __shfl(l_run, lh * 4 + r);
    int s = q0 + w * 16 + lh * 4 + r;
#pragma unroll
    for (int ni = 0; ni < 4; ++ni) {
      int dh = ni * 16 + lr;
      ao[((size_t)(b * 2048 + s)) * 512 + h * 64 + dh] = (__bf16)(oacc[ni][r] * linv);
    }
  }
}

extern "C" void kernel_launch(void* const* d_in, const int* in_sizes, int n_in,
                              void* d_out, int out_size, void* d_ws, size_t ws_size,
                              hipStream_t stream) {
  (void)in_sizes; (void)n_in; (void)out_size; (void)ws_size;
  const float* hs = (const float*)d_in[0];
  const float* Wq = (const float*)d_in[1];
  const float* Wk = (const float*)d_in[2];
  const float* Wv = (const float*)d_in[3];
  const float* Wo = (const float*)d_in[4];
  const float* rb = (const float*)d_in[5];
  char* ws = (char*)d_ws;
  __bf16* hs2    = (__bf16*)(ws + OFF_HS2);
  __bf16* wqkv2  = (__bf16*)(ws + OFF_WQKV2);
  __bf16* wo_t   = (__bf16*)(ws + OFF_WO);
  __bf16* qhb    = (__bf16*)(ws + OFF_QH);
  __bf16* qlb    = (__bf16*)(ws + OFF_QL);
  __bf16* kb     = (__bf16*)(ws + OFF_K);
  __bf16* vtb    = (__bf16*)(ws + OFF_VT);
  __bf16* aob    = (__bf16*)(ws + OFF_AO);
  float*  bias   = (float*)(ws + OFF_BIAS);

  k_prep<<<dim3(8, 8, 36), 256, 0, stream>>>(hs, Wq, Wk, Wv, Wo, rb, hs2, wqkv2, wo_t, bias);
  k_gemm<0, 48, 1024, 1536><<<768, 256, 0, stream>>>(hs2, wqkv2, qhb, qlb, kb, vtb, nullptr);
  k_attn<<<dim3(512), 512, 0, stream>>>(qhb, qlb, kb, vtb, bias, aob);
  k_gemm<1, 16, 512, 512><<<dim3(4, 64), 256, 0, stream>>>(aob, wo_t, nullptr, nullptr, nullptr, nullptr, (float*)d_out);
}

// Round 19
// 117.830 us; speedup vs baseline: 1.0445x; 1.0445x over previous
//
#include <hip/hip_runtime.h>
#include <stdint.h>

typedef __attribute__((ext_vector_type(8))) __bf16 bf16x8;
typedef __attribute__((ext_vector_type(4))) __bf16 bf16x4;
typedef __attribute__((ext_vector_type(4))) float f32x4;
typedef __attribute__((ext_vector_type(4))) unsigned int u32x4;

#define SEQ 2048
#define LOG2E 1.4426950408889634f

// ---------- ws layout (bytes) ----------
#define OFF_HS2   0ull               // bf16 [8192][1024]
#define OFF_AO    8388608ull         // bf16 [8192][512] (overlay; hs2 dead after QKV GEMM)
#define OFF_WQKV2 16777216ull        // bf16 [1536][1536]
#define OFF_WO    21495808ull        // bf16 [512][512]
#define OFF_QH    22020096ull        // bf16 [32][2048][64]
#define OFF_QL    30408704ull
#define OFF_K     38797312ull
#define OFF_VT    47185920ull        // bf16 [32][64][2048] (GEMM epilogue, s-permuted)
#define OFF_BIAS  55574528ull        // f32 [8][4096] (log2e-scaled)

__device__ __forceinline__ int swz(int row) { return ((row & 7) << 4) ^ ((row & 8) << 1); }

__device__ __forceinline__ void gl_lds16(const void* g, void* l) {
  __builtin_amdgcn_global_load_lds(
      (__attribute__((address_space(1))) void*)(uintptr_t)g,
      (__attribute__((address_space(3))) void*)(uint32_t)(uintptr_t)l, 16, 0, 0);
}

__device__ __forceinline__ float fast_exp2(float x) { return __builtin_amdgcn_exp2f(x); }

// ---------- prep: weights (z<3 split QKV / z==3 Wo+bias) and hs cast (z>=4) ----------
__global__ void k_prep(const float* __restrict__ hs,
                       const float* __restrict__ Wq, const float* __restrict__ Wk,
                       const float* __restrict__ Wv, const float* __restrict__ Wo,
                       const float* __restrict__ rel_bias,
                       __bf16* __restrict__ hs2, __bf16* __restrict__ w2,
                       __bf16* __restrict__ wo_t, float* __restrict__ bias_tab) {
  int z = blockIdx.z;
  if (z >= 4) {
    int cid = (z - 4) * 64 + blockIdx.y * 8 + blockIdx.x;
    int gid = cid * 256 + threadIdx.x;
    int row = gid >> 6, c8 = (gid & 63) * 8;
    const float* p = hs + (size_t)row * 512 + c8;
    float4 a = *(const float4*)p, b = *(const float4*)(p + 4);
    float v[8] = {a.x, a.y, a.z, a.w, b.x, b.y, b.z, b.w};
    bf16x8 hi, lo;
#pragma unroll
    for (int j = 0; j < 8; ++j) {
      __bf16 h = (__bf16)v[j];
      hi[j] = h;
      lo[j] = (__bf16)(v[j] - (float)h);
    }
    *(bf16x8*)(hs2 + (size_t)row * 1024 + c8) = hi;
    *(bf16x8*)(hs2 + (size_t)row * 1024 + 512 + c8) = lo;
    return;
  }
  __shared__ float tile[64][65];
  const float* W = (z == 0) ? Wq : (z == 1) ? Wk : (z == 2) ? Wv : Wo;
  int k0 = blockIdx.y * 64, n0 = blockIdx.x * 64;
  int tx = threadIdx.x & 63, ty = threadIdx.x >> 6;
  for (int r = ty; r < 64; r += 4) tile[r][tx] = W[(size_t)(k0 + r) * 512 + n0 + tx];
  __syncthreads();
  if (z < 3) {
    float scale = (z == 0) ? LOG2E : 1.0f;
    for (int r = ty; r < 64; r += 4) {
      float v = tile[tx][r] * scale;
      __bf16 h = (__bf16)v;
      __bf16 lo = (__bf16)(v - (float)h);
      __bf16* dst = w2 + (size_t)(z * 512 + n0 + r) * 1536;
      dst[k0 + tx] = h;
      dst[512 + k0 + tx] = h;
      dst[1024 + k0 + tx] = lo;
    }
  } else {
    for (int r = ty; r < 64; r += 4)
      wo_t[(size_t)(n0 + r) * 512 + k0 + tx] = (__bf16)tile[tx][r];
    int blk = blockIdx.y * 8 + blockIdx.x;
#pragma unroll
    for (int e = 0; e < 2; ++e) {
      int idx = blk * 512 + e * 256 + threadIdx.x;
      int h = idx >> 12, dIdx = idx & 4095;
      float v = 0.f;
      if (dIdx < 4095) {
        int d = dIdx - 2047;
        int rp = d < 0 ? -d : d;
        int bp;
        if (rp < 8) bp = rp;
        else bp = 8 + (rp >= 12) + (rp >= 16) + (rp >= 23) + (rp >= 32) + (rp >= 46) + (rp >= 64) + (rp >= 91);
        v = rel_bias[((d > 0 ? 16 : 0) + bp) * 8 + h] * LOG2E;
      }
      bias_tab[idx] = v;
    }
  }
}

// ---------- GEMM; MODE 0: class-ordered grid (Q 48, K 32, V 16 K-steps), V writes vt ----------
template <int MODE, int KSTEPS, int LDA, int LDB>
__global__ __launch_bounds__(256) void k_gemm(const __bf16* __restrict__ A,
                                              const __bf16* __restrict__ Bt,
                                              __bf16* __restrict__ qh, __bf16* __restrict__ ql,
                                              __bf16* __restrict__ ko, __bf16* __restrict__ vt,
                                              float* __restrict__ fo) {
  __shared__ __align__(16) __bf16 As[2][128 * 32];
  __shared__ __align__(16) __bf16 Bs[2][128 * 32];
  int tid = threadIdx.x, w = tid >> 6, l = tid & 63;
  int lr = l & 15, lh = l >> 4;
  int m0, n0, ksteps;
  if (MODE == 0) {
    int flat = blockIdx.x;                      // 768 blocks, heavy-Q class first
    int C = flat >> 8, local = flat & 255;
    int local2 = (local & 7) * 32 + (local >> 3);
    m0 = (local2 >> 2) * 128;
    n0 = ((C << 2) | (local2 & 3)) * 128;
    ksteps = (C == 0) ? 48 : (C == 1) ? 32 : 16;
  } else {
    int nwg = gridDim.x * gridDim.y;
    int flat = blockIdx.y * gridDim.x + blockIdx.x;
    int flat2 = (flat & 7) * (nwg >> 3) + (flat >> 3);
    m0 = (flat2 / gridDim.x) * 128;
    n0 = (flat2 % gridDim.x) * 128;
    ksteps = KSTEPS;
  }
  int wm = (w >> 1) * 64, wn = (w & 1) * 64;
  f32x4 zero4 = {0.f, 0.f, 0.f, 0.f};
  f32x4 acc[4][4];
#pragma unroll
  for (int i = 0; i < 4; ++i)
#pragma unroll
    for (int j = 0; j < 4; ++j) acc[i][j] = zero4;

  auto stage = [&](int kt, int buf) {
    int ka = (MODE == 0 && kt >= 32) ? kt - 32 : kt;
#pragma unroll
    for (int c = 0; c < 2; ++c) {
      int i = c * 256 + w * 64 + l;
      int row = i >> 2, cc = i & 3;
      gl_lds16(A + (size_t)(m0 + row) * LDA + ka * 32 + cc * 8,
               (char*)&As[buf][0] + (c * 256 + w * 64) * 16);
      gl_lds16(Bt + (size_t)(n0 + row) * LDB + kt * 32 + cc * 8,
               (char*)&Bs[buf][0] + (c * 256 + w * 64) * 16);
    }
  };

  stage(0, 0);
  __syncthreads();
#pragma unroll 2
  for (int kt = 0; kt < ksteps; ++kt) {
    int cur = kt & 1;
    if (kt + 1 < ksteps) stage(kt + 1, cur ^ 1);
    bf16x8 af[4], bfr[4];
#pragma unroll
    for (int mi = 0; mi < 4; ++mi)
      af[mi] = *(const bf16x8*)&As[cur][(wm + mi * 16 + lr) * 32 + lh * 8];
#pragma unroll
    for (int ni = 0; ni < 4; ++ni)
      bfr[ni] = *(const bf16x8*)&Bs[cur][(wn + ni * 16 + lr) * 32 + lh * 8];
#pragma unroll
    for (int mi = 0; mi < 4; ++mi)
#pragma unroll
      for (int ni = 0; ni < 4; ++ni)
        acc[mi][ni] = __builtin_amdgcn_mfma_f32_16x16x32_bf16(af[mi], bfr[ni], acc[mi][ni], 0, 0, 0);
    __syncthreads();
  }

  if (MODE == 0 && n0 >= 1024) {
    // V epilogue: write transposed + s-permuted directly into vt[bh][dh][s']
#pragma unroll
    for (int mi = 0; mi < 4; ++mi)
#pragma unroll
      for (int ni = 0; ni < 4; ++ni) {
        int m = m0 + wm + mi * 16 + lh * 4;
        int n = n0 + wn + ni * 16 + lr;
        int c9 = n & 511, hh = c9 >> 6, dh = c9 & 63;
        int b = m >> 11, s = m & 2047;
        int loc = s & 63;
        int pp = ((loc >> 5) << 5) | (((loc >> 2) & 3) << 3) | (((loc >> 4) & 1) << 2);
        bf16x4 o;
#pragma unroll
        for (int r = 0; r < 4; ++r) o[r] = (__bf16)acc[mi][ni][r];
        *(bf16x4*)&vt[((size_t)(b * 8 + hh) * 64 + dh) * 2048 + (s & ~63) + pp] = o;
      }
    return;
  }

#pragma unroll
  for (int mi = 0; mi < 4; ++mi)
#pragma unroll
    for (int ni = 0; ni < 4; ++ni)
#pragma unroll
      for (int r = 0; r < 4; ++r) {
        int m = m0 + wm + mi * 16 + lh * 4 + r;
        int n = n0 + wn + ni * 16 + lr;
        float vv = acc[mi][ni][r];
        if (MODE == 0) {
          int which = n >> 9, c9 = n & 511, hh = c9 >> 6, dh = c9 & 63;
          int b = m >> 11, s = m & 2047;
          size_t o = (size_t)((b * 8 + hh) * 2048 + s) * 64 + dh;
          if (which == 0) {
            __bf16 hv = (__bf16)vv;
            qh[o] = hv;
            ql[o] = (__bf16)(vv - (float)hv);
          } else {
            ko[o] = (__bf16)vv;
          }
        } else {
          fo[(size_t)m * 512 + n] = vv;
        }
      }
}

// ---------- flash attention: swapped QK^T, bias-as-C, STATIC-SHIFT exp (no online max) ----------
// Range analysis: scores ~ N(0,64) natural -> |S_log2| < ~90 << f32/bf16 exponent range.
// exp2(S) never overflows/underflows harmfully; normalization divides scale out exactly.
__global__ __launch_bounds__(512) void k_attn(const __bf16* __restrict__ qhp,
                                              const __bf16* __restrict__ qlp,
                                              const __bf16* __restrict__ k,
                                              const __bf16* __restrict__ vt,
                                              const float* __restrict__ bias_tab,
                                              __bf16* __restrict__ ao) {
  __shared__ __align__(16) __bf16 Ks[4][64 * 64];
  __shared__ __align__(16) __bf16 Vs[4][64 * 64];
  __shared__ float bias_s[2176];
  int tid = threadIdx.x, w = tid >> 6, l = tid & 63;
  int lr = l & 15, lh = l >> 4;
  int d = blockIdx.x;
  int bh = (d & 7) + ((d >> 3) & 3) * 8;
  int q0 = (d >> 5) * 128;
  int h = bh & 7, b = bh >> 3;
  const char* kbase = (const char*)(k + (size_t)bh * SEQ * 64);
  const char* vbase = (const char*)(vt + (size_t)bh * 64 * SEQ);

  float bR = bias_tab[h * 4096 + 2047 + 200];
  float bL = bias_tab[h * 4096 + 2047 - 200];

  for (int j = tid; j < 2176; j += 512)
    bias_s[j] = bias_tab[h * 4096 + (1920 - q0) + j];

  auto stageKV = [&](int kt, int buf) {
    const char* kb = kbase + (size_t)kt * 64 * 128;
    const char* vb = vbase + (size_t)kt * 128;
    int row = tid >> 3, colb = (tid & 7) * 16;
    gl_lds16(kb + row * 128 + (colb ^ swz(row)), (char*)&Ks[buf][0] + tid * 16);
    gl_lds16(vb + (size_t)row * 4096 + (colb ^ swz(row)), (char*)&Vs[buf][0] + tid * 16);
  };

  // Q fragments straight from global
  bf16x8 qfh[2], qfl[2];
  int qrow = w * 16 + lr;
  {
    const __bf16* qg = qhp + ((size_t)bh * SEQ + q0 + qrow) * 64;
    qfh[0] = *(const bf16x8*)(qg + lh * 8);
    qfh[1] = *(const bf16x8*)(qg + 32 + lh * 8);
    const __bf16* qg2 = qlp + ((size_t)bh * SEQ + q0 + qrow) * 64;
    qfl[0] = *(const bf16x8*)(qg2 + lh * 8);
    qfl[1] = *(const bf16x8*)(qg2 + 32 + lh * 8);
  }

  float l_run = 0.f;
  f32x4 zero4 = {0.f, 0.f, 0.f, 0.f};
  f32x4 oacc[4];
#pragma unroll
  for (int i = 0; i < 4; ++i) oacc[i] = zero4;

  auto compute = [&](int kt, int buf) {
    // bias folds into the MFMA C operand (per-element near the diagonal, splat far)
    int dmin = kt * 64 - q0 - 127, dmax = kt * 64 + 63 - q0;
    bool far = (dmin >= 91) || (dmax <= -91);
    f32x4 cinit[4];
    if (far) {
      float cb = (dmin >= 91) ? bR : bL;
#pragma unroll
      for (int t = 0; t < 4; ++t)
#pragma unroll
        for (int r = 0; r < 4; ++r) cinit[t][r] = cb;
    } else {
      int jb = kt * 64 + lh * 4 + 127 - (w * 16 + lr);
#pragma unroll
      for (int t = 0; t < 4; ++t)
#pragma unroll
        for (int r = 0; r < 4; ++r) cinit[t][r] = bias_s[jb + t * 16 + r];
    }
    const char* kb = (const char*)&Ks[buf][0];
    f32x4 sacc[4];
    __builtin_amdgcn_s_setprio(1);
#pragma unroll
    for (int t = 0; t < 4; ++t) {
      int row = t * 16 + lr;
      bf16x8 b0 = *(const bf16x8*)(kb + row * 128 + ((lh * 16) ^ swz(row)));
      bf16x8 b1 = *(const bf16x8*)(kb + row * 128 + ((64 + lh * 16) ^ swz(row)));
      f32x4 z = cinit[t];
      z = __builtin_amdgcn_mfma_f32_16x16x32_bf16(b0, qfh[0], z, 0, 0, 0);
      z = __builtin_amdgcn_mfma_f32_16x16x32_bf16(b1, qfh[1], z, 0, 0, 0);
      z = __builtin_amdgcn_mfma_f32_16x16x32_bf16(b0, qfl[0], z, 0, 0, 0);
      z = __builtin_amdgcn_mfma_f32_16x16x32_bf16(b1, qfl[1], z, 0, 0, 0);
      sacc[t] = z;
    }
    __builtin_amdgcn_s_setprio(0);
    // static-shift softmax: p = 2^S directly; scale divides out in the final normalize
    float p[4][4];
    float rt[4];
#pragma unroll
    for (int t = 0; t < 4; ++t) {
#pragma unroll
      for (int r = 0; r < 4; ++r) p[t][r] = fast_exp2(sacc[t][r]);
      rt[t] = (p[t][0] + p[t][1]) + (p[t][2] + p[t][3]);
    }
    l_run += (rt[0] + rt[1]) + (rt[2] + rt[3]);
    uint32_t pk[4][2];
#pragma unroll
    for (int t = 0; t < 4; ++t) {
      asm("v_cvt_pk_bf16_f32 %0, %1, %2" : "=v"(pk[t][0]) : "v"(p[t][0]), "v"(p[t][1]));
      asm("v_cvt_pk_bf16_f32 %0, %1, %2" : "=v"(pk[t][1]) : "v"(p[t][2]), "v"(p[t][3]));
    }
    u32x4 A0 = {pk[0][0], pk[0][1], pk[1][0], pk[1][1]};
    u32x4 A1 = {pk[2][0], pk[2][1], pk[3][0], pk[3][1]};
    bf16x8 pa0 = __builtin_bit_cast(bf16x8, A0);
    bf16x8 pa1 = __builtin_bit_cast(bf16x8, A1);
    const char* vbr = (const char*)&Vs[buf][0];
    __builtin_amdgcn_s_setprio(1);
#pragma unroll
    for (int ni = 0; ni < 4; ++ni) {
      int vrow = ni * 16 + lr;
      bf16x8 v0 = *(const bf16x8*)(vbr + vrow * 128 + ((lh * 16) ^ swz(vrow)));
      bf16x8 v1 = *(const bf16x8*)(vbr + vrow * 128 + ((64 + lh * 16) ^ swz(vrow)));
      oacc[ni] = __builtin_amdgcn_mfma_f32_16x16x32_bf16(pa0, v0, oacc[ni], 0, 0, 0);
      oacc[ni] = __builtin_amdgcn_mfma_f32_16x16x32_bf16(pa1, v1, oacc[ni], 0, 0, 0);
    }
    __builtin_amdgcn_s_setprio(0);
  };

  // 4-buffer pipeline: one barrier per 2 kt
  stageKV(0, 0);
  stageKV(1, 1);
  __syncthreads();
#pragma unroll 2
  for (int kp = 0; kp < 16; ++kp) {
    int rb_ = (kp & 1) * 2;
    if (kp < 15) {
      stageKV(2 * kp + 2, rb_ ^ 2);
      stageKV(2 * kp + 3, (rb_ ^ 2) + 1);
    }
    compute(2 * kp, rb_);
    compute(2 * kp + 1, rb_ + 1);
    __syncthreads();
  }

  // one-time class reduce of per-lane l partials
  l_run += __shfl_xor(l_run, 16);
  l_run += __shfl_xor(l_run, 32);

#pragma unroll
  for (int r = 0; r < 4; ++r) {
    float linv = 1.0f / __shfl(l_run, lh * 4 + r);
    int s = q0 + w * 16 + lh * 4 + r;
#pragma unroll
    for (int ni = 0; ni < 4; ++ni) {
      int dh = ni * 16 + lr;
      ao[((size_t)(b * 2048 + s)) * 512 + h * 64 + dh] = (__bf16)(oacc[ni][r] * linv);
    }
  }
}

extern "C" void kernel_launch(void* const* d_in, const int* in_sizes, int n_in,
                              void* d_out, int out_size, void* d_ws, size_t ws_size,
                              hipStream_t stream) {
  (void)in_sizes; (void)n_in; (void)out_size; (void)ws_size;
  const float* hs = (const float*)d_in[0];
  const float* Wq = (const float*)d_in[1];
  const float* Wk = (const float*)d_in[2];
  const float* Wv = (const float*)d_in[3];
  const float* Wo = (const float*)d_in[4];
  const float* rb = (const float*)d_in[5];
  char* ws = (char*)d_ws;
  __bf16* hs2    = (__bf16*)(ws + OFF_HS2);
  __bf16* wqkv2  = (__bf16*)(ws + OFF_WQKV2);
  __bf16* wo_t   = (__bf16*)(ws + OFF_WO);
  __bf16* qhb    = (__bf16*)(ws + OFF_QH);
  __bf16* qlb    = (__bf16*)(ws + OFF_QL);
  __bf16* kb     = (__bf16*)(ws + OFF_K);
  __bf16* vtb    = (__bf16*)(ws + OFF_VT);
  __bf16* aob    = (__bf16*)(ws + OFF_AO);
  float*  bias   = (float*)(ws + OFF_BIAS);

  k_prep<<<dim3(8, 8, 36), 256, 0, stream>>>(hs, Wq, Wk, Wv, Wo, rb, hs2, wqkv2, wo_t, bias);
  k_gemm<0, 48, 1024, 1536><<<768, 256, 0, stream>>>(hs2, wqkv2, qhb, qlb, kb, vtb, nullptr);
  k_attn<<<dim3(512), 512, 0, stream>>>(qhb, qlb, kb, vtb, bias, aob);
  k_gemm<1, 16, 512, 512><<<dim3(4, 64), 256, 0, stream>>>(aob, wo_t, nullptr, nullptr, nullptr, nullptr, (float*)d_out);
}

// Round 20
// 112.979 us; speedup vs baseline: 1.0894x; 1.0429x over previous
//
#include <hip/hip_runtime.h>
#include <stdint.h>

typedef __attribute__((ext_vector_type(8))) __bf16 bf16x8;
typedef __attribute__((ext_vector_type(4))) __bf16 bf16x4;
typedef __attribute__((ext_vector_type(4))) float f32x4;
typedef __attribute__((ext_vector_type(4))) unsigned int u32x4;

#define SEQ 2048
#define LOG2E 1.4426950408889634f

// ---------- ws layout (bytes) ----------
#define OFF_HS2   0ull               // bf16 [8192][1024]
#define OFF_AO    8388608ull         // bf16 [8192][512] (overlay; hs2 dead after QKV GEMM)
#define OFF_WQKV2 16777216ull        // bf16 [1536][1536]
#define OFF_WO    21495808ull        // bf16 [512][512]
#define OFF_QH    22020096ull        // bf16 [32][2048][64]
#define OFF_QL    30408704ull
#define OFF_K     38797312ull
#define OFF_VT    47185920ull        // bf16 [32][64][2048] (GEMM epilogue, s-permuted)
#define OFF_BIAS  55574528ull        // f32 [8][4096] (log2e-scaled)

__device__ __forceinline__ int swz(int row) { return ((row & 7) << 4) ^ ((row & 8) << 1); }

__device__ __forceinline__ void gl_lds16(const void* g, void* l) {
  __builtin_amdgcn_global_load_lds(
      (__attribute__((address_space(1))) void*)(uintptr_t)g,
      (__attribute__((address_space(3))) void*)(uint32_t)(uintptr_t)l, 16, 0, 0);
}

__device__ __forceinline__ float fast_exp2(float x) { return __builtin_amdgcn_exp2f(x); }

// ---------- prep: weights (z<3 split QKV / z==3 Wo+bias) and hs cast (z>=4) ----------
__global__ void k_prep(const float* __restrict__ hs,
                       const float* __restrict__ Wq, const float* __restrict__ Wk,
                       const float* __restrict__ Wv, const float* __restrict__ Wo,
                       const float* __restrict__ rel_bias,
                       __bf16* __restrict__ hs2, __bf16* __restrict__ w2,
                       __bf16* __restrict__ wo_t, float* __restrict__ bias_tab) {
  int z = blockIdx.z;
  if (z >= 4) {
    int cid = (z - 4) * 64 + blockIdx.y * 8 + blockIdx.x;
    int gid = cid * 256 + threadIdx.x;
    int row = gid >> 6, c8 = (gid & 63) * 8;
    const float* p = hs + (size_t)row * 512 + c8;
    float4 a = *(const float4*)p, b = *(const float4*)(p + 4);
    float v[8] = {a.x, a.y, a.z, a.w, b.x, b.y, b.z, b.w};
    bf16x8 hi, lo;
#pragma unroll
    for (int j = 0; j < 8; ++j) {
      __bf16 h = (__bf16)v[j];
      hi[j] = h;
      lo[j] = (__bf16)(v[j] - (float)h);
    }
    *(bf16x8*)(hs2 + (size_t)row * 1024 + c8) = hi;
    *(bf16x8*)(hs2 + (size_t)row * 1024 + 512 + c8) = lo;
    return;
  }
  __shared__ float tile[64][65];
  const float* W = (z == 0) ? Wq : (z == 1) ? Wk : (z == 2) ? Wv : Wo;
  int k0 = blockIdx.y * 64, n0 = blockIdx.x * 64;
  int tx = threadIdx.x & 63, ty = threadIdx.x >> 6;
  for (int r = ty; r < 64; r += 4) tile[r][tx] = W[(size_t)(k0 + r) * 512 + n0 + tx];
  __syncthreads();
  if (z < 3) {
    float scale = (z == 0) ? LOG2E : 1.0f;
    for (int r = ty; r < 64; r += 4) {
      float v = tile[tx][r] * scale;
      __bf16 h = (__bf16)v;
      __bf16 lo = (__bf16)(v - (float)h);
      __bf16* dst = w2 + (size_t)(z * 512 + n0 + r) * 1536;
      dst[k0 + tx] = h;
      dst[512 + k0 + tx] = h;
      dst[1024 + k0 + tx] = lo;
    }
  } else {
    for (int r = ty; r < 64; r += 4)
      wo_t[(size_t)(n0 + r) * 512 + k0 + tx] = (__bf16)tile[tx][r];
    int blk = blockIdx.y * 8 + blockIdx.x;
#pragma unroll
    for (int e = 0; e < 2; ++e) {
      int idx = blk * 512 + e * 256 + threadIdx.x;
      int h = idx >> 12, dIdx = idx & 4095;
      float v = 0.f;
      if (dIdx < 4095) {
        int d = dIdx - 2047;
        int rp = d < 0 ? -d : d;
        int bp;
        if (rp < 8) bp = rp;
        else bp = 8 + (rp >= 12) + (rp >= 16) + (rp >= 23) + (rp >= 32) + (rp >= 46) + (rp >= 64) + (rp >= 91);
        v = rel_bias[((d > 0 ? 16 : 0) + bp) * 8 + h] * LOG2E;
      }
      bias_tab[idx] = v;
    }
  }
}

// ---------- GEMM; MODE 0: class-ordered grid (Q 48, K 32, V 16 K-steps), V writes vt ----------
template <int MODE, int KSTEPS, int LDA, int LDB>
__global__ __launch_bounds__(256) void k_gemm(const __bf16* __restrict__ A,
                                              const __bf16* __restrict__ Bt,
                                              __bf16* __restrict__ qh, __bf16* __restrict__ ql,
                                              __bf16* __restrict__ ko, __bf16* __restrict__ vt,
                                              float* __restrict__ fo) {
  __shared__ __align__(16) __bf16 As[2][128 * 32];
  __shared__ __align__(16) __bf16 Bs[2][128 * 32];
  int tid = threadIdx.x, w = tid >> 6, l = tid & 63;
  int lr = l & 15, lh = l >> 4;
  int m0, n0, ksteps;
  if (MODE == 0) {
    int flat = blockIdx.x;                      // 768 blocks, heavy-Q class first
    int C = flat >> 8, local = flat & 255;
    int local2 = (local & 7) * 32 + (local >> 3);
    m0 = (local2 >> 2) * 128;
    n0 = ((C << 2) | (local2 & 3)) * 128;
    ksteps = (C == 0) ? 48 : (C == 1) ? 32 : 16;
  } else {
    int nwg = gridDim.x * gridDim.y;
    int flat = blockIdx.y * gridDim.x + blockIdx.x;
    int flat2 = (flat & 7) * (nwg >> 3) + (flat >> 3);
    m0 = (flat2 / gridDim.x) * 128;
    n0 = (flat2 % gridDim.x) * 128;
    ksteps = KSTEPS;
  }
  int wm = (w >> 1) * 64, wn = (w & 1) * 64;
  f32x4 zero4 = {0.f, 0.f, 0.f, 0.f};
  f32x4 acc[4][4];
#pragma unroll
  for (int i = 0; i < 4; ++i)
#pragma unroll
    for (int j = 0; j < 4; ++j) acc[i][j] = zero4;

  auto stage = [&](int kt, int buf) {
    int ka = (MODE == 0 && kt >= 32) ? kt - 32 : kt;
#pragma unroll
    for (int c = 0; c < 2; ++c) {
      int i = c * 256 + w * 64 + l;
      int row = i >> 2, cc = i & 3;
      gl_lds16(A + (size_t)(m0 + row) * LDA + ka * 32 + cc * 8,
               (char*)&As[buf][0] + (c * 256 + w * 64) * 16);
      gl_lds16(Bt + (size_t)(n0 + row) * LDB + kt * 32 + cc * 8,
               (char*)&Bs[buf][0] + (c * 256 + w * 64) * 16);
    }
  };

  stage(0, 0);
  __syncthreads();
#pragma unroll 2
  for (int kt = 0; kt < ksteps; ++kt) {
    int cur = kt & 1;
    if (kt + 1 < ksteps) stage(kt + 1, cur ^ 1);
    bf16x8 af[4], bfr[4];
#pragma unroll
    for (int mi = 0; mi < 4; ++mi)
      af[mi] = *(const bf16x8*)&As[cur][(wm + mi * 16 + lr) * 32 + lh * 8];
#pragma unroll
    for (int ni = 0; ni < 4; ++ni)
      bfr[ni] = *(const bf16x8*)&Bs[cur][(wn + ni * 16 + lr) * 32 + lh * 8];
#pragma unroll
    for (int mi = 0; mi < 4; ++mi)
#pragma unroll
      for (int ni = 0; ni < 4; ++ni)
        acc[mi][ni] = __builtin_amdgcn_mfma_f32_16x16x32_bf16(af[mi], bfr[ni], acc[mi][ni], 0, 0, 0);
    __syncthreads();
  }

  if (MODE == 0 && n0 >= 1024) {
    // V epilogue: write transposed + s-permuted directly into vt[bh][dh][s']
#pragma unroll
    for (int mi = 0; mi < 4; ++mi)
#pragma unroll
      for (int ni = 0; ni < 4; ++ni) {
        int m = m0 + wm + mi * 16 + lh * 4;
        int n = n0 + wn + ni * 16 + lr;
        int c9 = n & 511, hh = c9 >> 6, dh = c9 & 63;
        int b = m >> 11, s = m & 2047;
        int loc = s & 63;
        int pp = ((loc >> 5) << 5) | (((loc >> 2) & 3) << 3) | (((loc >> 4) & 1) << 2);
        bf16x4 o;
#pragma unroll
        for (int r = 0; r < 4; ++r) o[r] = (__bf16)acc[mi][ni][r];
        *(bf16x4*)&vt[((size_t)(b * 8 + hh) * 64 + dh) * 2048 + (s & ~63) + pp] = o;
      }
    return;
  }

#pragma unroll
  for (int mi = 0; mi < 4; ++mi)
#pragma unroll
    for (int ni = 0; ni < 4; ++ni)
#pragma unroll
      for (int r = 0; r < 4; ++r) {
        int m = m0 + wm + mi * 16 + lh * 4 + r;
        int n = n0 + wn + ni * 16 + lr;
        float vv = acc[mi][ni][r];
        if (MODE == 0) {
          int which = n >> 9, c9 = n & 511, hh = c9 >> 6, dh = c9 & 63;
          int b = m >> 11, s = m & 2047;
          size_t o = (size_t)((b * 8 + hh) * 2048 + s) * 64 + dh;
          if (which == 0) {
            __bf16 hv = (__bf16)vv;
            qh[o] = hv;
            ql[o] = (__bf16)(vv - (float)hv);
          } else {
            ko[o] = (__bf16)vv;
          }
        } else {
          fo[(size_t)m * 512 + n] = vv;
        }
      }
}

// ---------- flash attention: QBLK=256 (32 q-rows/wave), K/V fragments reused 2x ----------
__global__ __launch_bounds__(512) void k_attn(const __bf16* __restrict__ qhp,
                                              const __bf16* __restrict__ qlp,
                                              const __bf16* __restrict__ k,
                                              const __bf16* __restrict__ vt,
                                              const float* __restrict__ bias_tab,
                                              __bf16* __restrict__ ao) {
  __shared__ __align__(16) __bf16 Ks[4][64 * 64];
  __shared__ __align__(16) __bf16 Vs[4][64 * 64];
  __shared__ float bias_s[2304];                 // d in [-q0-255 .. 2047-q0] window
  int tid = threadIdx.x, w = tid >> 6, l = tid & 63;
  int lr = l & 15, lh = l >> 4;
  int d = blockIdx.x;                            // 256 blocks (1/CU)
  int bh = (d & 7) + ((d >> 3) & 3) * 8;
  int q0 = (d >> 5) * 256;
  int h = bh & 7, b = bh >> 3;
  const char* kbase = (const char*)(k + (size_t)bh * SEQ * 64);
  const char* vbase = (const char*)(vt + (size_t)bh * 64 * SEQ);

  float bR = bias_tab[h * 4096 + 2047 + 200];
  float bL = bias_tab[h * 4096 + 2047 - 200];

  for (int j = tid; j < 2304; j += 512)
    bias_s[j] = bias_tab[h * 4096 + (1792 - q0) + j];   // bias at d = j - 255 - q0 + ... (window shifted)

  auto stageKV = [&](int kt, int buf) {
    const char* kb = kbase + (size_t)kt * 64 * 128;
    const char* vb = vbase + (size_t)kt * 128;
    int row = tid >> 3, colb = (tid & 7) * 16;
    gl_lds16(kb + row * 128 + (colb ^ swz(row)), (char*)&Ks[buf][0] + tid * 16);
    gl_lds16(vb + (size_t)row * 4096 + (colb ^ swz(row)), (char*)&Vs[buf][0] + tid * 16);
  };

  // Q fragments (2 q-sets of 16 rows each) straight from global
  bf16x8 qfh[2][2], qfl[2][2];
#pragma unroll
  for (int qs = 0; qs < 2; ++qs) {
    int qrow = w * 32 + qs * 16 + lr;
    const __bf16* qg = qhp + ((size_t)bh * SEQ + q0 + qrow) * 64;
    qfh[qs][0] = *(const bf16x8*)(qg + lh * 8);
    qfh[qs][1] = *(const bf16x8*)(qg + 32 + lh * 8);
    const __bf16* qg2 = qlp + ((size_t)bh * SEQ + q0 + qrow) * 64;
    qfl[qs][0] = *(const bf16x8*)(qg2 + lh * 8);
    qfl[qs][1] = *(const bf16x8*)(qg2 + 32 + lh * 8);
  }

  float l_run0 = 0.f, l_run1 = 0.f;
  f32x4 zero4 = {0.f, 0.f, 0.f, 0.f};
  f32x4 oacc[2][4];
#pragma unroll
  for (int qs = 0; qs < 2; ++qs)
#pragma unroll
    for (int i = 0; i < 4; ++i) oacc[qs][i] = zero4;

  auto compute = [&](int kt, int buf) {
    int dmin = kt * 64 - q0 - 255, dmax = kt * 64 + 63 - q0;
    bool far = (dmin >= 91) || (dmax <= -91);
    f32x4 cinit[2][4];
    if (far) {
      float cb = (dmin >= 91) ? bR : bL;
#pragma unroll
      for (int qs = 0; qs < 2; ++qs)
#pragma unroll
        for (int t = 0; t < 4; ++t)
#pragma unroll
          for (int r = 0; r < 4; ++r) cinit[qs][t][r] = cb;
    } else {
#pragma unroll
      for (int qs = 0; qs < 2; ++qs) {
        int jb = kt * 64 + lh * 4 + 255 - (w * 32 + qs * 16 + lr);
#pragma unroll
        for (int t = 0; t < 4; ++t)
#pragma unroll
          for (int r = 0; r < 4; ++r) cinit[qs][t][r] = bias_s[jb + t * 16 + r];
      }
    }
    const char* kb = (const char*)&Ks[buf][0];
    f32x4 sacc[2][4];
    __builtin_amdgcn_s_setprio(1);
#pragma unroll
    for (int t = 0; t < 4; ++t) {
      int row = t * 16 + lr;
      bf16x8 b0 = *(const bf16x8*)(kb + row * 128 + ((lh * 16) ^ swz(row)));
      bf16x8 b1 = *(const bf16x8*)(kb + row * 128 + ((64 + lh * 16) ^ swz(row)));
#pragma unroll
      for (int qs = 0; qs < 2; ++qs) {
        f32x4 z = cinit[qs][t];
        z = __builtin_amdgcn_mfma_f32_16x16x32_bf16(b0, qfh[qs][0], z, 0, 0, 0);
        z = __builtin_amdgcn_mfma_f32_16x16x32_bf16(b1, qfh[qs][1], z, 0, 0, 0);
        z = __builtin_amdgcn_mfma_f32_16x16x32_bf16(b0, qfl[qs][0], z, 0, 0, 0);
        z = __builtin_amdgcn_mfma_f32_16x16x32_bf16(b1, qfl[qs][1], z, 0, 0, 0);
        sacc[qs][t] = z;
      }
    }
    __builtin_amdgcn_s_setprio(0);
    // static-shift softmax per q-set
    bf16x8 paA[2], paB[2];
#pragma unroll
    for (int qs = 0; qs < 2; ++qs) {
      float p[4][4];
      float rt[4];
#pragma unroll
      for (int t = 0; t < 4; ++t) {
#pragma unroll
        for (int r = 0; r < 4; ++r) p[t][r] = fast_exp2(sacc[qs][t][r]);
        rt[t] = (p[t][0] + p[t][1]) + (p[t][2] + p[t][3]);
      }
      if (qs == 0) l_run0 += (rt[0] + rt[1]) + (rt[2] + rt[3]);
      else         l_run1 += (rt[0] + rt[1]) + (rt[2] + rt[3]);
      uint32_t pk[4][2];
#pragma unroll
      for (int t = 0; t < 4; ++t) {
        asm("v_cvt_pk_bf16_f32 %0, %1, %2" : "=v"(pk[t][0]) : "v"(p[t][0]), "v"(p[t][1]));
        asm("v_cvt_pk_bf16_f32 %0, %1, %2" : "=v"(pk[t][1]) : "v"(p[t][2]), "v"(p[t][3]));
      }
      u32x4 A0 = {pk[0][0], pk[0][1], pk[1][0], pk[1][1]};
      u32x4 A1 = {pk[2][0], pk[2][1], pk[3][0], pk[3][1]};
      paA[qs] = __builtin_bit_cast(bf16x8, A0);
      paB[qs] = __builtin_bit_cast(bf16x8, A1);
    }
    const char* vbr = (const char*)&Vs[buf][0];
    __builtin_amdgcn_s_setprio(1);
#pragma unroll
    for (int ni = 0; ni < 4; ++ni) {
      int vrow = ni * 16 + lr;
      bf16x8 v0 = *(const bf16x8*)(vbr + vrow * 128 + ((lh * 16) ^ swz(vrow)));
      bf16x8 v1 = *(const bf16x8*)(vbr + vrow * 128 + ((64 + lh * 16) ^ swz(vrow)));
#pragma unroll
      for (int qs = 0; qs < 2; ++qs) {
        oacc[qs][ni] = __builtin_amdgcn_mfma_f32_16x16x32_bf16(paA[qs], v0, oacc[qs][ni], 0, 0, 0);
        oacc[qs][ni] = __builtin_amdgcn_mfma_f32_16x16x32_bf16(paB[qs], v1, oacc[qs][ni], 0, 0, 0);
      }
    }
    __builtin_amdgcn_s_setprio(0);
  };

  // 4-buffer pipeline: one barrier per 2 kt (prefetch issued 2 computes ahead)
  stageKV(0, 0);
  stageKV(1, 1);
  __syncthreads();
#pragma unroll 2
  for (int kp = 0; kp < 16; ++kp) {
    int rb_ = (kp & 1) * 2;
    if (kp < 15) {
      stageKV(2 * kp + 2, rb_ ^ 2);
      stageKV(2 * kp + 3, (rb_ ^ 2) + 1);
    }
    compute(2 * kp, rb_);
    compute(2 * kp + 1, rb_ + 1);
    __syncthreads();
  }

  // one-time class reduce of per-lane l partials
  l_run0 += __shfl_xor(l_run0, 16);
  l_run0 += __shfl_xor(l_run0, 32);
  l_run1 += __shfl_xor(l_run1, 16);
  l_run1 += __shfl_xor(l_run1, 32);

#pragma unroll
  for (int qs = 0; qs < 2; ++qs) {
    float lsel = (qs == 0) ? l_run0 : l_run1;
#pragma unroll
    for (int r = 0; r < 4; ++r) {
      float linv = 1.0f / __shfl(lsel, lh * 4 + r);
      int s = q0 + w * 32 + qs * 16 + lh * 4 + r;
#pragma unroll
      for (int ni = 0; ni < 4; ++ni) {
        int dh = ni * 16 + lr;
        ao[((size_t)(b * 2048 + s)) * 512 + h * 64 + dh] = (__bf16)(oacc[qs][ni][r] * linv);
      }
    }
  }
}

extern "C" void kernel_launch(void* const* d_in, const int* in_sizes, int n_in,
                              void* d_out, int out_size, void* d_ws, size_t ws_size,
                              hipStream_t stream) {
  (void)in_sizes; (void)n_in; (void)out_size; (void)ws_size;
  const float* hs = (const float*)d_in[0];
  const float* Wq = (const float*)d_in[1];
  const float* Wk = (const float*)d_in[2];
  const float* Wv = (const float*)d_in[3];
  const float* Wo = (const float*)d_in[4];
  const float* rb = (const float*)d_in[5];
  char* ws = (char*)d_ws;
  __bf16* hs2    = (__bf16*)(ws + OFF_HS2);
  __bf16* wqkv2  = (__bf16*)(ws + OFF_WQKV2);
  __bf16* wo_t   = (__bf16*)(ws + OFF_WO);
  __bf16* qhb    = (__bf16*)(ws + OFF_QH);
  __bf16* qlb    = (__bf16*)(ws + OFF_QL);
  __bf16* kb     = (__bf16*)(ws + OFF_K);
  __bf16* vtb    = (__bf16*)(ws + OFF_VT);
  __bf16* aob    = (__bf16*)(ws + OFF_AO);
  float*  bias   = (float*)(ws + OFF_BIAS);

  k_prep<<<dim3(8, 8, 36), 256, 0, stream>>>(hs, Wq, Wk, Wv, Wo, rb, hs2, wqkv2, wo_t, bias);
  k_gemm<0, 48, 1024, 1536><<<768, 256, 0, stream>>>(hs2, wqkv2, qhb, qlb, kb, vtb, nullptr);
  k_attn<<<dim3(256), 512, 0, stream>>>(qhb, qlb, kb, vtb, bias, aob);
  k_gemm<1, 16, 512, 512><<<dim3(4, 64), 256, 0, stream>>>(aob, wo_t, nullptr, nullptr, nullptr, nullptr, (float*)d_out);
}

// Round 21
// 112.835 us; speedup vs baseline: 1.0908x; 1.0013x over previous
//
#include <hip/hip_runtime.h>
#include <stdint.h>

typedef __attribute__((ext_vector_type(8))) __bf16 bf16x8;
typedef __attribute__((ext_vector_type(4))) __bf16 bf16x4;
typedef __attribute__((ext_vector_type(4))) float f32x4;
typedef __attribute__((ext_vector_type(4))) unsigned int u32x4;

#define SEQ 2048
#define LOG2E 1.4426950408889634f

// ---------- ws layout (bytes) ----------
#define OFF_HS2   0ull               // bf16 [8192][1024]
#define OFF_AO    8388608ull         // bf16 [8192][512] (overlay; hs2 dead after QKV GEMM)
#define OFF_WQKV2 16777216ull        // bf16 [1536][1536]
#define OFF_WO    21495808ull        // bf16 [512][512]
#define OFF_QH    22020096ull        // bf16 [32][2048][64]
#define OFF_QL    30408704ull
#define OFF_K     38797312ull
#define OFF_VT    47185920ull        // bf16 [32][64][2048] (GEMM epilogue, s-permuted)
#define OFF_BIAS  55574528ull        // f32 [8][4096] (log2e-scaled)

__device__ __forceinline__ int swz(int row) { return ((row & 7) << 4) ^ ((row & 8) << 1); }

__device__ __forceinline__ void gl_lds16(const void* g, void* l) {
  __builtin_amdgcn_global_load_lds(
      (__attribute__((address_space(1))) void*)(uintptr_t)g,
      (__attribute__((address_space(3))) void*)(uint32_t)(uintptr_t)l, 16, 0, 0);
}

__device__ __forceinline__ float fast_exp2(float x) { return __builtin_amdgcn_exp2f(x); }

// ---------- prep: weights (z<3 split QKV / z==3 Wo+bias) and hs cast (z>=4) ----------
__global__ void k_prep(const float* __restrict__ hs,
                       const float* __restrict__ Wq, const float* __restrict__ Wk,
                       const float* __restrict__ Wv, const float* __restrict__ Wo,
                       const float* __restrict__ rel_bias,
                       __bf16* __restrict__ hs2, __bf16* __restrict__ w2,
                       __bf16* __restrict__ wo_t, float* __restrict__ bias_tab) {
  int z = blockIdx.z;
  if (z >= 4) {
    int cid = (z - 4) * 64 + blockIdx.y * 8 + blockIdx.x;
    int gid = cid * 256 + threadIdx.x;
    int row = gid >> 6, c8 = (gid & 63) * 8;
    const float* p = hs + (size_t)row * 512 + c8;
    float4 a = *(const float4*)p, b = *(const float4*)(p + 4);
    float v[8] = {a.x, a.y, a.z, a.w, b.x, b.y, b.z, b.w};
    bf16x8 hi, lo;
#pragma unroll
    for (int j = 0; j < 8; ++j) {
      __bf16 h = (__bf16)v[j];
      hi[j] = h;
      lo[j] = (__bf16)(v[j] - (float)h);
    }
    *(bf16x8*)(hs2 + (size_t)row * 1024 + c8) = hi;
    *(bf16x8*)(hs2 + (size_t)row * 1024 + 512 + c8) = lo;
    return;
  }
  __shared__ float tile[64][65];
  const float* W = (z == 0) ? Wq : (z == 1) ? Wk : (z == 2) ? Wv : Wo;
  int k0 = blockIdx.y * 64, n0 = blockIdx.x * 64;
  int tx = threadIdx.x & 63, ty = threadIdx.x >> 6;
  for (int r = ty; r < 64; r += 4) tile[r][tx] = W[(size_t)(k0 + r) * 512 + n0 + tx];
  __syncthreads();
  if (z < 3) {
    float scale = (z == 0) ? LOG2E : 1.0f;
    for (int r = ty; r < 64; r += 4) {
      float v = tile[tx][r] * scale;
      __bf16 h = (__bf16)v;
      __bf16 lo = (__bf16)(v - (float)h);
      __bf16* dst = w2 + (size_t)(z * 512 + n0 + r) * 1536;
      dst[k0 + tx] = h;
      dst[512 + k0 + tx] = h;
      dst[1024 + k0 + tx] = lo;
    }
  } else {
    for (int r = ty; r < 64; r += 4)
      wo_t[(size_t)(n0 + r) * 512 + k0 + tx] = (__bf16)tile[tx][r];
    int blk = blockIdx.y * 8 + blockIdx.x;
#pragma unroll
    for (int e = 0; e < 2; ++e) {
      int idx = blk * 512 + e * 256 + threadIdx.x;
      int h = idx >> 12, dIdx = idx & 4095;
      float v = 0.f;
      if (dIdx < 4095) {
        int d = dIdx - 2047;
        int rp = d < 0 ? -d : d;
        int bp;
        if (rp < 8) bp = rp;
        else bp = 8 + (rp >= 12) + (rp >= 16) + (rp >= 23) + (rp >= 32) + (rp >= 46) + (rp >= 64) + (rp >= 91);
        v = rel_bias[((d > 0 ? 16 : 0) + bp) * 8 + h] * LOG2E;
      }
      bias_tab[idx] = v;
    }
  }
}

// ---------- GEMM; MODE 0: class-ordered grid (Q 48, K 32, V 16 K-steps), V writes vt ----------
template <int MODE, int KSTEPS, int LDA, int LDB>
__global__ __launch_bounds__(256) void k_gemm(const __bf16* __restrict__ A,
                                              const __bf16* __restrict__ Bt,
                                              __bf16* __restrict__ qh, __bf16* __restrict__ ql,
                                              __bf16* __restrict__ ko, __bf16* __restrict__ vt,
                                              float* __restrict__ fo) {
  __shared__ __align__(16) __bf16 As[2][128 * 32];
  __shared__ __align__(16) __bf16 Bs[2][128 * 32];
  int tid = threadIdx.x, w = tid >> 6, l = tid & 63;
  int lr = l & 15, lh = l >> 4;
  int m0, n0, ksteps;
  if (MODE == 0) {
    int flat = blockIdx.x;                      // 768 blocks, heavy-Q class first
    int C = flat >> 8, local = flat & 255;
    int local2 = (local & 7) * 32 + (local >> 3);
    m0 = (local2 >> 2) * 128;
    n0 = ((C << 2) | (local2 & 3)) * 128;
    ksteps = (C == 0) ? 48 : (C == 1) ? 32 : 16;
  } else {
    int nwg = gridDim.x * gridDim.y;
    int flat = blockIdx.y * gridDim.x + blockIdx.x;
    int flat2 = (flat & 7) * (nwg >> 3) + (flat >> 3);
    m0 = (flat2 / gridDim.x) * 128;
    n0 = (flat2 % gridDim.x) * 128;
    ksteps = KSTEPS;
  }
  int wm = (w >> 1) * 64, wn = (w & 1) * 64;
  f32x4 zero4 = {0.f, 0.f, 0.f, 0.f};
  f32x4 acc[4][4];
#pragma unroll
  for (int i = 0; i < 4; ++i)
#pragma unroll
    for (int j = 0; j < 4; ++j) acc[i][j] = zero4;

  auto stage = [&](int kt, int buf) {
    int ka = (MODE == 0 && kt >= 32) ? kt - 32 : kt;
#pragma unroll
    for (int c = 0; c < 2; ++c) {
      int i = c * 256 + w * 64 + l;
      int row = i >> 2, cc = i & 3;
      gl_lds16(A + (size_t)(m0 + row) * LDA + ka * 32 + cc * 8,
               (char*)&As[buf][0] + (c * 256 + w * 64) * 16);
      gl_lds16(Bt + (size_t)(n0 + row) * LDB + kt * 32 + cc * 8,
               (char*)&Bs[buf][0] + (c * 256 + w * 64) * 16);
    }
  };

  stage(0, 0);
  __syncthreads();
#pragma unroll 2
  for (int kt = 0; kt < ksteps; ++kt) {
    int cur = kt & 1;
    if (kt + 1 < ksteps) stage(kt + 1, cur ^ 1);
    bf16x8 af[4], bfr[4];
#pragma unroll
    for (int mi = 0; mi < 4; ++mi)
      af[mi] = *(const bf16x8*)&As[cur][(wm + mi * 16 + lr) * 32 + lh * 8];
#pragma unroll
    for (int ni = 0; ni < 4; ++ni)
      bfr[ni] = *(const bf16x8*)&Bs[cur][(wn + ni * 16 + lr) * 32 + lh * 8];
#pragma unroll
    for (int mi = 0; mi < 4; ++mi)
#pragma unroll
      for (int ni = 0; ni < 4; ++ni)
        acc[mi][ni] = __builtin_amdgcn_mfma_f32_16x16x32_bf16(af[mi], bfr[ni], acc[mi][ni], 0, 0, 0);
    __syncthreads();
  }

  if (MODE == 0 && n0 >= 1024) {
    // V epilogue: write transposed + s-permuted directly into vt[bh][dh][s']
#pragma unroll
    for (int mi = 0; mi < 4; ++mi)
#pragma unroll
      for (int ni = 0; ni < 4; ++ni) {
        int m = m0 + wm + mi * 16 + lh * 4;
        int n = n0 + wn + ni * 16 + lr;
        int c9 = n & 511, hh = c9 >> 6, dh = c9 & 63;
        int b = m >> 11, s = m & 2047;
        int loc = s & 63;
        int pp = ((loc >> 5) << 5) | (((loc >> 2) & 3) << 3) | (((loc >> 4) & 1) << 2);
        bf16x4 o;
#pragma unroll
        for (int r = 0; r < 4; ++r) o[r] = (__bf16)acc[mi][ni][r];
        *(bf16x4*)&vt[((size_t)(b * 8 + hh) * 64 + dh) * 2048 + (s & ~63) + pp] = o;
      }
    return;
  }

#pragma unroll
  for (int mi = 0; mi < 4; ++mi)
#pragma unroll
    for (int ni = 0; ni < 4; ++ni)
#pragma unroll
      for (int r = 0; r < 4; ++r) {
        int m = m0 + wm + mi * 16 + lh * 4 + r;
        int n = n0 + wn + ni * 16 + lr;
        float vv = acc[mi][ni][r];
        if (MODE == 0) {
          int which = n >> 9, c9 = n & 511, hh = c9 >> 6, dh = c9 & 63;
          int b = m >> 11, s = m & 2047;
          size_t o = (size_t)((b * 8 + hh) * 2048 + s) * 64 + dh;
          if (which == 0) {
            __bf16 hv = (__bf16)vv;
            qh[o] = hv;
            ql[o] = (__bf16)(vv - (float)hv);
          } else {
            ko[o] = (__bf16)vv;
          }
        } else {
          fo[(size_t)m * 512 + n] = vv;
        }
      }
}

// ---------- flash attention: QBLK=256, QK(kt & kt+1) issued ahead of softmax/PV ----------
__global__ __launch_bounds__(512) void k_attn(const __bf16* __restrict__ qhp,
                                              const __bf16* __restrict__ qlp,
                                              const __bf16* __restrict__ k,
                                              const __bf16* __restrict__ vt,
                                              const float* __restrict__ bias_tab,
                                              __bf16* __restrict__ ao) {
  __shared__ __align__(16) __bf16 Ks[4][64 * 64];
  __shared__ __align__(16) __bf16 Vs[4][64 * 64];
  __shared__ float bias_s[2304];
  int tid = threadIdx.x, w = tid >> 6, l = tid & 63;
  int lr = l & 15, lh = l >> 4;
  int d = blockIdx.x;                            // 256 blocks (1/CU)
  int bh = (d & 7) + ((d >> 3) & 3) * 8;
  int q0 = (d >> 5) * 256;
  int h = bh & 7, b = bh >> 3;
  const char* kbase = (const char*)(k + (size_t)bh * SEQ * 64);
  const char* vbase = (const char*)(vt + (size_t)bh * 64 * SEQ);

  float bR = bias_tab[h * 4096 + 2047 + 200];
  float bL = bias_tab[h * 4096 + 2047 - 200];

  for (int j = tid; j < 2304; j += 512)
    bias_s[j] = bias_tab[h * 4096 + (1792 - q0) + j];

  auto stageKV = [&](int kt, int buf) {
    const char* kb = kbase + (size_t)kt * 64 * 128;
    const char* vb = vbase + (size_t)kt * 128;
    int row = tid >> 3, colb = (tid & 7) * 16;
    gl_lds16(kb + row * 128 + (colb ^ swz(row)), (char*)&Ks[buf][0] + tid * 16);
    gl_lds16(vb + (size_t)row * 4096 + (colb ^ swz(row)), (char*)&Vs[buf][0] + tid * 16);
  };

  // Q fragments (2 q-sets of 16 rows each) straight from global
  bf16x8 qfh[2][2], qfl[2][2];
#pragma unroll
  for (int qs = 0; qs < 2; ++qs) {
    int qrow = w * 32 + qs * 16 + lr;
    const __bf16* qg = qhp + ((size_t)bh * SEQ + q0 + qrow) * 64;
    qfh[qs][0] = *(const bf16x8*)(qg + lh * 8);
    qfh[qs][1] = *(const bf16x8*)(qg + 32 + lh * 8);
    const __bf16* qg2 = qlp + ((size_t)bh * SEQ + q0 + qrow) * 64;
    qfl[qs][0] = *(const bf16x8*)(qg2 + lh * 8);
    qfl[qs][1] = *(const bf16x8*)(qg2 + 32 + lh * 8);
  }

  float l_run0 = 0.f, l_run1 = 0.f;
  f32x4 zero4 = {0.f, 0.f, 0.f, 0.f};
  f32x4 oacc[2][4];
#pragma unroll
  for (int qs = 0; qs < 2; ++qs)
#pragma unroll
    for (int i = 0; i < 4; ++i) oacc[qs][i] = zero4;

  // QK phase: bias C-init + 32 MFMAs into sacc (results consumed later)
  auto qk = [&](int kt, int buf, f32x4 (&sacc)[2][4]) {
    int dmin = kt * 64 - q0 - 255, dmax = kt * 64 + 63 - q0;
    bool far = (dmin >= 91) || (dmax <= -91);
    f32x4 cinit[2][4];
    if (far) {
      float cb = (dmin >= 91) ? bR : bL;
#pragma unroll
      for (int qs = 0; qs < 2; ++qs)
#pragma unroll
        for (int t = 0; t < 4; ++t)
#pragma unroll
          for (int r = 0; r < 4; ++r) cinit[qs][t][r] = cb;
    } else {
#pragma unroll
      for (int qs = 0; qs < 2; ++qs) {
        int jb = kt * 64 + lh * 4 + 255 - (w * 32 + qs * 16 + lr);
#pragma unroll
        for (int t = 0; t < 4; ++t)
#pragma unroll
          for (int r = 0; r < 4; ++r) cinit[qs][t][r] = bias_s[jb + t * 16 + r];
      }
    }
    const char* kb = (const char*)&Ks[buf][0];
    __builtin_amdgcn_s_setprio(1);
#pragma unroll
    for (int t = 0; t < 4; ++t) {
      int row = t * 16 + lr;
      bf16x8 b0 = *(const bf16x8*)(kb + row * 128 + ((lh * 16) ^ swz(row)));
      bf16x8 b1 = *(const bf16x8*)(kb + row * 128 + ((64 + lh * 16) ^ swz(row)));
#pragma unroll
      for (int qs = 0; qs < 2; ++qs) {
        f32x4 z = cinit[qs][t];
        z = __builtin_amdgcn_mfma_f32_16x16x32_bf16(b0, qfh[qs][0], z, 0, 0, 0);
        z = __builtin_amdgcn_mfma_f32_16x16x32_bf16(b1, qfh[qs][1], z, 0, 0, 0);
        z = __builtin_amdgcn_mfma_f32_16x16x32_bf16(b0, qfl[qs][0], z, 0, 0, 0);
        z = __builtin_amdgcn_mfma_f32_16x16x32_bf16(b1, qfl[qs][1], z, 0, 0, 0);
        sacc[qs][t] = z;
      }
    }
    __builtin_amdgcn_s_setprio(0);
  };

  // finish phase: static-shift softmax + PV
  auto finish = [&](int kt, int buf, f32x4 (&sacc)[2][4]) {
    (void)kt;
    bf16x8 paA[2], paB[2];
#pragma unroll
    for (int qs = 0; qs < 2; ++qs) {
      float p[4][4];
      float rt[4];
#pragma unroll
      for (int t = 0; t < 4; ++t) {
#pragma unroll
        for (int r = 0; r < 4; ++r) p[t][r] = fast_exp2(sacc[qs][t][r]);
        rt[t] = (p[t][0] + p[t][1]) + (p[t][2] + p[t][3]);
      }
      if (qs == 0) l_run0 += (rt[0] + rt[1]) + (rt[2] + rt[3]);
      else         l_run1 += (rt[0] + rt[1]) + (rt[2] + rt[3]);
      uint32_t pk[4][2];
#pragma unroll
      for (int t = 0; t < 4; ++t) {
        asm("v_cvt_pk_bf16_f32 %0, %1, %2" : "=v"(pk[t][0]) : "v"(p[t][0]), "v"(p[t][1]));
        asm("v_cvt_pk_bf16_f32 %0, %1, %2" : "=v"(pk[t][1]) : "v"(p[t][2]), "v"(p[t][3]));
      }
      u32x4 A0 = {pk[0][0], pk[0][1], pk[1][0], pk[1][1]};
      u32x4 A1 = {pk[2][0], pk[2][1], pk[3][0], pk[3][1]};
      paA[qs] = __builtin_bit_cast(bf16x8, A0);
      paB[qs] = __builtin_bit_cast(bf16x8, A1);
    }
    const char* vbr = (const char*)&Vs[buf][0];
    __builtin_amdgcn_s_setprio(1);
#pragma unroll
    for (int ni = 0; ni < 4; ++ni) {
      int vrow = ni * 16 + lr;
      bf16x8 v0 = *(const bf16x8*)(vbr + vrow * 128 + ((lh * 16) ^ swz(vrow)));
      bf16x8 v1 = *(const bf16x8*)(vbr + vrow * 128 + ((64 + lh * 16) ^ swz(vrow)));
#pragma unroll
      for (int qs = 0; qs < 2; ++qs) {
        oacc[qs][ni] = __builtin_amdgcn_mfma_f32_16x16x32_bf16(paA[qs], v0, oacc[qs][ni], 0, 0, 0);
        oacc[qs][ni] = __builtin_amdgcn_mfma_f32_16x16x32_bf16(paB[qs], v1, oacc[qs][ni], 0, 0, 0);
      }
    }
    __builtin_amdgcn_s_setprio(0);
  };

  // 4-buffer pipeline, same barrier skeleton as r20; QK batches issued ahead of finishes
  stageKV(0, 0);
  stageKV(1, 1);
  __syncthreads();
  f32x4 sA[2][4], sB[2][4];
#pragma unroll 2
  for (int kp = 0; kp < 16; ++kp) {
    int rb_ = (kp & 1) * 2;
    qk(2 * kp, rb_, sA);
    qk(2 * kp + 1, rb_ + 1, sB);
    if (kp < 15) {
      stageKV(2 * kp + 2, rb_ ^ 2);
      stageKV(2 * kp + 3, (rb_ ^ 2) + 1);
    }
    finish(2 * kp, rb_, sA);
    finish(2 * kp + 1, rb_ + 1, sB);
    __syncthreads();
  }

  // one-time class reduce of per-lane l partials
  l_run0 += __shfl_xor(l_run0, 16);
  l_run0 += __shfl_xor(l_run0, 32);
  l_run1 += __shfl_xor(l_run1, 16);
  l_run1 += __shfl_xor(l_run1, 32);

#pragma unroll
  for (int qs = 0; qs < 2; ++qs) {
    float lsel = (qs == 0) ? l_run0 : l_run1;
#pragma unroll
    for (int r = 0; r < 4; ++r) {
      float linv = 1.0f / __shfl(lsel, lh * 4 + r);
      int s = q0 + w * 32 + qs * 16 + lh * 4 + r;
#pragma unroll
      for (int ni = 0; ni < 4; ++ni) {
        int dh = ni * 16 + lr;
        ao[((size_t)(b * 2048 + s)) * 512 + h * 64 + dh] = (__bf16)(oacc[qs][ni][r] * linv);
      }
    }
  }
}

extern "C" void kernel_launch(void* const* d_in, const int* in_sizes, int n_in,
                              void* d_out, int out_size, void* d_ws, size_t ws_size,
                              hipStream_t stream) {
  (void)in_sizes; (void)n_in; (void)out_size; (void)ws_size;
  const float* hs = (const float*)d_in[0];
  const float* Wq = (const float*)d_in[1];
  const float* Wk = (const float*)d_in[2];
  const float* Wv = (const float*)d_in[3];
  const float* Wo = (const float*)d_in[4];
  const float* rb = (const float*)d_in[5];
  char* ws = (char*)d_ws;
  __bf16* hs2    = (__bf16*)(ws + OFF_HS2);
  __bf16* wqkv2  = (__bf16*)(ws + OFF_WQKV2);
  __bf16* wo_t   = (__bf16*)(ws + OFF_WO);
  __bf16* qhb    = (__bf16*)(ws + OFF_QH);
  __bf16* qlb    = (__bf16*)(ws + OFF_QL);
  __bf16* kb     = (__bf16*)(ws + OFF_K);
  __bf16* vtb    = (__bf16*)(ws + OFF_VT);
  __bf16* aob    = (__bf16*)(ws + OFF_AO);
  float*  bias   = (float*)(ws + OFF_BIAS);

  k_prep<<<dim3(8, 8, 36), 256, 0, stream>>>(hs, Wq, Wk, Wv, Wo, rb, hs2, wqkv2, wo_t, bias);
  k_gemm<0, 48, 1024, 1536><<<768, 256, 0, stream>>>(hs2, wqkv2, qhb, qlb, kb, vtb, nullptr);
  k_attn<<<dim3(256), 512, 0, stream>>>(qhb, qlb, kb, vtb, bias, aob);
  k_gemm<1, 16, 512, 512><<<dim3(4, 64), 256, 0, stream>>>(aob, wo_t, nullptr, nullptr, nullptr, nullptr, (float*)d_out);
}

// Round 22
// 89.994 us; speedup vs baseline: 1.3676x; 1.2538x over previous
//
#include <hip/hip_runtime.h>
#include <stdint.h>

typedef __attribute__((ext_vector_type(8))) __bf16 bf16x8;
typedef __attribute__((ext_vector_type(4))) __bf16 bf16x4;
typedef __attribute__((ext_vector_type(8))) _Float16 f16x8;
typedef __attribute__((ext_vector_type(4))) float f32x4;
typedef __attribute__((ext_vector_type(4))) unsigned int u32x4;

#define SEQ 2048
#define LOG2E 1.4426950408889634f

// ---------- ws layout (bytes) ----------
#define OFF_HSF   0ull               // fp16 [8192][512]; AO overlays after GEMM0
#define OFF_AO    0ull               // bf16 [8192][512] (attn out; HSF dead by then)
#define OFF_WF    8388608ull         // fp16 [1536][512] (transposed QKV weights; Wq pre-scaled log2e)
#define OFF_WO    9961472ull         // bf16 [512][512]
#define OFF_Q     10485760ull        // fp16 [32][2048][64]
#define OFF_K     18874368ull        // fp16 [32][2048][64]
#define OFF_VT    27262976ull        // bf16 [32][64][2048] (s-permuted)
#define OFF_BIAS  35651584ull        // f32 [8][4096] (log2e-scaled)

__device__ __forceinline__ int swz(int row) { return ((row & 7) << 4) ^ ((row & 8) << 1); }

__device__ __forceinline__ void gl_lds16(const void* g, void* l) {
  __builtin_amdgcn_global_load_lds(
      (__attribute__((address_space(1))) void*)(uintptr_t)g,
      (__attribute__((address_space(3))) void*)(uint32_t)(uintptr_t)l, 16, 0, 0);
}

__device__ __forceinline__ float fast_exp2(float x) { return __builtin_amdgcn_exp2f(x); }

// ---------- prep: weights (z<3 QKV fp16 / z==3 Wo+bias) and hs cast fp16 (z>=4) ----------
__global__ void k_prep(const float* __restrict__ hs,
                       const float* __restrict__ Wq, const float* __restrict__ Wk,
                       const float* __restrict__ Wv, const float* __restrict__ Wo,
                       const float* __restrict__ rel_bias,
                       _Float16* __restrict__ hsf, _Float16* __restrict__ wf,
                       __bf16* __restrict__ wo_t, float* __restrict__ bias_tab) {
  int z = blockIdx.z;
  if (z >= 4) {
    int cid = (z - 4) * 64 + blockIdx.y * 8 + blockIdx.x;
    int gid = cid * 256 + threadIdx.x;            // 524288 threads
    int row = gid >> 6, c8 = (gid & 63) * 8;
    const float* p = hs + (size_t)row * 512 + c8;
    float4 a = *(const float4*)p, b = *(const float4*)(p + 4);
    float v[8] = {a.x, a.y, a.z, a.w, b.x, b.y, b.z, b.w};
    f16x8 hv;
#pragma unroll
    for (int j = 0; j < 8; ++j) hv[j] = (_Float16)v[j];
    *(f16x8*)(hsf + (size_t)row * 512 + c8) = hv;
    return;
  }
  __shared__ float tile[64][65];
  const float* W = (z == 0) ? Wq : (z == 1) ? Wk : (z == 2) ? Wv : Wo;
  int k0 = blockIdx.y * 64, n0 = blockIdx.x * 64;
  int tx = threadIdx.x & 63, ty = threadIdx.x >> 6;
  for (int r = ty; r < 64; r += 4) tile[r][tx] = W[(size_t)(k0 + r) * 512 + n0 + tx];
  __syncthreads();
  if (z < 3) {
    float scale = (z == 0) ? LOG2E : 1.0f;
    for (int r = ty; r < 64; r += 4)
      wf[(size_t)(z * 512 + n0 + r) * 512 + k0 + tx] = (_Float16)(tile[tx][r] * scale);
  } else {
    for (int r = ty; r < 64; r += 4)
      wo_t[(size_t)(n0 + r) * 512 + k0 + tx] = (__bf16)tile[tx][r];
    int blk = blockIdx.y * 8 + blockIdx.x;
#pragma unroll
    for (int e = 0; e < 2; ++e) {
      int idx = blk * 512 + e * 256 + threadIdx.x;
      int h = idx >> 12, dIdx = idx & 4095;
      float v = 0.f;
      if (dIdx < 4095) {
        int d = dIdx - 2047;
        int rp = d < 0 ? -d : d;
        int bp;
        if (rp < 8) bp = rp;
        else bp = 8 + (rp >= 12) + (rp >= 16) + (rp >= 23) + (rp >= 32) + (rp >= 46) + (rp >= 64) + (rp >= 91);
        v = rel_bias[((d > 0 ? 16 : 0) + bp) * 8 + h] * LOG2E;
      }
      bias_tab[idx] = v;
    }
  }
}

// ---------- GEMM; MODE 0: fp16 single-pass QKV (16 ksteps), MODE 1: bf16 O-proj ----------
template <int MODE, int KSTEPS, int LDA, int LDB>
__global__ __launch_bounds__(256) void k_gemm(const void* __restrict__ Ap,
                                              const void* __restrict__ Btp,
                                              _Float16* __restrict__ qf,
                                              _Float16* __restrict__ kf,
                                              __bf16* __restrict__ vt,
                                              float* __restrict__ fo) {
  __shared__ __align__(16) char As[2][128 * 32 * 2];
  __shared__ __align__(16) char Bs[2][128 * 32 * 2];
  const char* A = (const char*)Ap;
  const char* Bt = (const char*)Btp;
  int tid = threadIdx.x, w = tid >> 6, l = tid & 63;
  int lr = l & 15, lh = l >> 4;
  // XCD-aware bijective remap (nwg % 8 == 0 for both modes)
  int nwg = gridDim.x * gridDim.y;
  int flat = blockIdx.y * gridDim.x + blockIdx.x;
  int flat2 = (flat & 7) * (nwg >> 3) + (flat >> 3);
  int m0 = (flat2 / gridDim.x) * 128, n0 = (flat2 % gridDim.x) * 128;
  int wm = (w >> 1) * 64, wn = (w & 1) * 64;
  f32x4 zero4 = {0.f, 0.f, 0.f, 0.f};
  f32x4 acc[4][4];
#pragma unroll
  for (int i = 0; i < 4; ++i)
#pragma unroll
    for (int j = 0; j < 4; ++j) acc[i][j] = zero4;

  auto stage = [&](int kt, int buf) {
#pragma unroll
    for (int c = 0; c < 2; ++c) {
      int i = c * 256 + w * 64 + l;
      int row = i >> 2, cc = i & 3;
      gl_lds16(A + ((size_t)(m0 + row) * LDA + kt * 32 + cc * 8) * 2,
               &As[buf][(c * 256 + w * 64) * 16]);
      gl_lds16(Bt + ((size_t)(n0 + row) * LDB + kt * 32 + cc * 8) * 2,
               &Bs[buf][(c * 256 + w * 64) * 16]);
    }
  };

  stage(0, 0);
  __syncthreads();
#pragma unroll 2
  for (int kt = 0; kt < KSTEPS; ++kt) {
    int cur = kt & 1;
    if (kt + 1 < KSTEPS) stage(kt + 1, cur ^ 1);
    u32x4 af[4], bfr[4];
#pragma unroll
    for (int mi = 0; mi < 4; ++mi)
      af[mi] = *(const u32x4*)&As[cur][((wm + mi * 16 + lr) * 32 + lh * 8) * 2];
#pragma unroll
    for (int ni = 0; ni < 4; ++ni)
      bfr[ni] = *(const u32x4*)&Bs[cur][((wn + ni * 16 + lr) * 32 + lh * 8) * 2];
#pragma unroll
    for (int mi = 0; mi < 4; ++mi)
#pragma unroll
      for (int ni = 0; ni < 4; ++ni) {
        if (MODE == 0)
          acc[mi][ni] = __builtin_amdgcn_mfma_f32_16x16x32_f16(
              __builtin_bit_cast(f16x8, af[mi]), __builtin_bit_cast(f16x8, bfr[ni]),
              acc[mi][ni], 0, 0, 0);
        else
          acc[mi][ni] = __builtin_amdgcn_mfma_f32_16x16x32_bf16(
              __builtin_bit_cast(bf16x8, af[mi]), __builtin_bit_cast(bf16x8, bfr[ni]),
              acc[mi][ni], 0, 0, 0);
      }
    __syncthreads();
  }

  if (MODE == 0 && n0 >= 1024) {
    // V epilogue: write transposed + s-permuted bf16 into vt[bh][dh][s']
#pragma unroll
    for (int mi = 0; mi < 4; ++mi)
#pragma unroll
      for (int ni = 0; ni < 4; ++ni) {
        int m = m0 + wm + mi * 16 + lh * 4;
        int n = n0 + wn + ni * 16 + lr;
        int c9 = n & 511, hh = c9 >> 6, dh = c9 & 63;
        int b = m >> 11, s = m & 2047;
        int loc = s & 63;
        int pp = ((loc >> 5) << 5) | (((loc >> 2) & 3) << 3) | (((loc >> 4) & 1) << 2);
        bf16x4 o;
#pragma unroll
        for (int r = 0; r < 4; ++r) o[r] = (__bf16)acc[mi][ni][r];
        *(bf16x4*)&vt[((size_t)(b * 8 + hh) * 64 + dh) * 2048 + (s & ~63) + pp] = o;
      }
    return;
  }

#pragma unroll
  for (int mi = 0; mi < 4; ++mi)
#pragma unroll
    for (int ni = 0; ni < 4; ++ni)
#pragma unroll
      for (int r = 0; r < 4; ++r) {
        int m = m0 + wm + mi * 16 + lh * 4 + r;
        int n = n0 + wn + ni * 16 + lr;
        float vv = acc[mi][ni][r];
        if (MODE == 0) {
          int which = n >> 9, c9 = n & 511, hh = c9 >> 6, dh = c9 & 63;
          int b = m >> 11, s = m & 2047;
          size_t o = (size_t)((b * 8 + hh) * 2048 + s) * 64 + dh;
          if (which == 0) qf[o] = (_Float16)vv;
          else            kf[o] = (_Float16)vv;
        } else {
          fo[(size_t)m * 512 + n] = vv;
        }
      }
}

// ---------- flash attention: fp16 QK single-pass, QBLK=256, static-shift exp ----------
__global__ __launch_bounds__(512) void k_attn(const _Float16* __restrict__ qfp,
                                              const _Float16* __restrict__ kfp,
                                              const __bf16* __restrict__ vt,
                                              const float* __restrict__ bias_tab,
                                              __bf16* __restrict__ ao) {
  __shared__ __align__(16) char Ks[4][64 * 128];   // fp16 rows (64 elem * 2B)
  __shared__ __align__(16) char Vs[4][64 * 128];   // bf16 rows
  __shared__ float bias_s[2304];
  int tid = threadIdx.x, w = tid >> 6, l = tid & 63;
  int lr = l & 15, lh = l >> 4;
  int d = blockIdx.x;                              // 256 blocks (1/CU)
  int bh = (d & 7) + ((d >> 3) & 3) * 8;
  int q0 = (d >> 5) * 256;
  int h = bh & 7, b = bh >> 3;
  const char* kbase = (const char*)(kfp + (size_t)bh * SEQ * 64);
  const char* vbase = (const char*)(vt + (size_t)bh * 64 * SEQ);

  float bR = bias_tab[h * 4096 + 2047 + 200];
  float bL = bias_tab[h * 4096 + 2047 - 200];

  for (int j = tid; j < 2304; j += 512)
    bias_s[j] = bias_tab[h * 4096 + (1792 - q0) + j];

  auto stageKV = [&](int kt, int buf) {
    const char* kb = kbase + (size_t)kt * 64 * 128;
    const char* vb = vbase + (size_t)kt * 128;
    int row = tid >> 3, colb = (tid & 7) * 16;
    gl_lds16(kb + row * 128 + (colb ^ swz(row)), &Ks[buf][tid * 16]);
    gl_lds16(vb + (size_t)row * 4096 + (colb ^ swz(row)), &Vs[buf][tid * 16]);
  };

  // Q fragments (fp16, 2 q-sets of 16 rows) straight from global
  f16x8 qf[2][2];
#pragma unroll
  for (int qs = 0; qs < 2; ++qs) {
    int qrow = w * 32 + qs * 16 + lr;
    const _Float16* qg = qfp + ((size_t)bh * SEQ + q0 + qrow) * 64;
    qf[qs][0] = *(const f16x8*)(qg + lh * 8);
    qf[qs][1] = *(const f16x8*)(qg + 32 + lh * 8);
  }

  float l_run0 = 0.f, l_run1 = 0.f;
  f32x4 zero4 = {0.f, 0.f, 0.f, 0.f};
  f32x4 oacc[2][4];
#pragma unroll
  for (int qs = 0; qs < 2; ++qs)
#pragma unroll
    for (int i = 0; i < 4; ++i) oacc[qs][i] = zero4;

  // QK phase: bias C-init + 16 fp16 MFMAs into sacc
  auto qk = [&](int kt, int buf, f32x4 (&sacc)[2][4]) {
    int dmin = kt * 64 - q0 - 255, dmax = kt * 64 + 63 - q0;
    bool far = (dmin >= 91) || (dmax <= -91);
    f32x4 cinit[2][4];
    if (far) {
      float cb = (dmin >= 91) ? bR : bL;
#pragma unroll
      for (int qs = 0; qs < 2; ++qs)
#pragma unroll
        for (int t = 0; t < 4; ++t)
#pragma unroll
          for (int r = 0; r < 4; ++r) cinit[qs][t][r] = cb;
    } else {
#pragma unroll
      for (int qs = 0; qs < 2; ++qs) {
        int jb = kt * 64 + lh * 4 + 255 - (w * 32 + qs * 16 + lr);
#pragma unroll
        for (int t = 0; t < 4; ++t)
#pragma unroll
          for (int r = 0; r < 4; ++r) cinit[qs][t][r] = bias_s[jb + t * 16 + r];
      }
    }
    const char* kb = &Ks[buf][0];
    __builtin_amdgcn_s_setprio(1);
#pragma unroll
    for (int t = 0; t < 4; ++t) {
      int row = t * 16 + lr;
      f16x8 b0 = *(const f16x8*)(kb + row * 128 + ((lh * 16) ^ swz(row)));
      f16x8 b1 = *(const f16x8*)(kb + row * 128 + ((64 + lh * 16) ^ swz(row)));
#pragma unroll
      for (int qs = 0; qs < 2; ++qs) {
        f32x4 z = cinit[qs][t];
        z = __builtin_amdgcn_mfma_f32_16x16x32_f16(b0, qf[qs][0], z, 0, 0, 0);
        z = __builtin_amdgcn_mfma_f32_16x16x32_f16(b1, qf[qs][1], z, 0, 0, 0);
        sacc[qs][t] = z;
      }
    }
    __builtin_amdgcn_s_setprio(0);
  };

  // finish phase: static-shift softmax + bf16 PV
  auto finish = [&](int buf, f32x4 (&sacc)[2][4]) {
    bf16x8 paA[2], paB[2];
#pragma unroll
    for (int qs = 0; qs < 2; ++qs) {
      float p[4][4];
      float rt[4];
#pragma unroll
      for (int t = 0; t < 4; ++t) {
#pragma unroll
        for (int r = 0; r < 4; ++r) p[t][r] = fast_exp2(sacc[qs][t][r]);
        rt[t] = (p[t][0] + p[t][1]) + (p[t][2] + p[t][3]);
      }
      if (qs == 0) l_run0 += (rt[0] + rt[1]) + (rt[2] + rt[3]);
      else         l_run1 += (rt[0] + rt[1]) + (rt[2] + rt[3]);
      uint32_t pk[4][2];
#pragma unroll
      for (int t = 0; t < 4; ++t) {
        asm("v_cvt_pk_bf16_f32 %0, %1, %2" : "=v"(pk[t][0]) : "v"(p[t][0]), "v"(p[t][1]));
        asm("v_cvt_pk_bf16_f32 %0, %1, %2" : "=v"(pk[t][1]) : "v"(p[t][2]), "v"(p[t][3]));
      }
      u32x4 A0 = {pk[0][0], pk[0][1], pk[1][0], pk[1][1]};
      u32x4 A1 = {pk[2][0], pk[2][1], pk[3][0], pk[3][1]};
      paA[qs] = __builtin_bit_cast(bf16x8, A0);
      paB[qs] = __builtin_bit_cast(bf16x8, A1);
    }
    const char* vbr = &Vs[buf][0];
    __builtin_amdgcn_s_setprio(1);
#pragma unroll
    for (int ni = 0; ni < 4; ++ni) {
      int vrow = ni * 16 + lr;
      bf16x8 v0 = *(const bf16x8*)(vbr + vrow * 128 + ((lh * 16) ^ swz(vrow)));
      bf16x8 v1 = *(const bf16x8*)(vbr + vrow * 128 + ((64 + lh * 16) ^ swz(vrow)));
#pragma unroll
      for (int qs = 0; qs < 2; ++qs) {
        oacc[qs][ni] = __builtin_amdgcn_mfma_f32_16x16x32_bf16(paA[qs], v0, oacc[qs][ni], 0, 0, 0);
        oacc[qs][ni] = __builtin_amdgcn_mfma_f32_16x16x32_bf16(paB[qs], v1, oacc[qs][ni], 0, 0, 0);
      }
    }
    __builtin_amdgcn_s_setprio(0);
  };

  // 4-buffer pipeline, one barrier per 2 kt; QK batches issued ahead of finishes
  stageKV(0, 0);
  stageKV(1, 1);
  __syncthreads();
  f32x4 sA[2][4], sB[2][4];
#pragma unroll 2
  for (int kp = 0; kp < 16; ++kp) {
    int rb_ = (kp & 1) * 2;
    qk(2 * kp, rb_, sA);
    qk(2 * kp + 1, rb_ + 1, sB);
    if (kp < 15) {
      stageKV(2 * kp + 2, rb_ ^ 2);
      stageKV(2 * kp + 3, (rb_ ^ 2) + 1);
    }
    finish(rb_, sA);
    finish(rb_ + 1, sB);
    __syncthreads();
  }

  // one-time class reduce of per-lane l partials
  l_run0 += __shfl_xor(l_run0, 16);
  l_run0 += __shfl_xor(l_run0, 32);
  l_run1 += __shfl_xor(l_run1, 16);
  l_run1 += __shfl_xor(l_run1, 32);

#pragma unroll
  for (int qs = 0; qs < 2; ++qs) {
    float lsel = (qs == 0) ? l_run0 : l_run1;
#pragma unroll
    for (int r = 0; r < 4; ++r) {
      float linv = 1.0f / __shfl(lsel, lh * 4 + r);
      int s = q0 + w * 32 + qs * 16 + lh * 4 + r;
#pragma unroll
      for (int ni = 0; ni < 4; ++ni) {
        int dh = ni * 16 + lr;
        ao[((size_t)(b * 2048 + s)) * 512 + h * 64 + dh] = (__bf16)(oacc[qs][ni][r] * linv);
      }
    }
  }
}

extern "C" void kernel_launch(void* const* d_in, const int* in_sizes, int n_in,
                              void* d_out, int out_size, void* d_ws, size_t ws_size,
                              hipStream_t stream) {
  (void)in_sizes; (void)n_in; (void)out_size; (void)ws_size;
  const float* hs = (const float*)d_in[0];
  const float* Wq = (const float*)d_in[1];
  const float* Wk = (const float*)d_in[2];
  const float* Wv = (const float*)d_in[3];
  const float* Wo = (const float*)d_in[4];
  const float* rb = (const float*)d_in[5];
  char* ws = (char*)d_ws;
  _Float16* hsf  = (_Float16*)(ws + OFF_HSF);
  _Float16* wfb  = (_Float16*)(ws + OFF_WF);
  __bf16* wo_t   = (__bf16*)(ws + OFF_WO);
  _Float16* qfb  = (_Float16*)(ws + OFF_Q);
  _Float16* kfb  = (_Float16*)(ws + OFF_K);
  __bf16* vtb    = (__bf16*)(ws + OFF_VT);
  __bf16* aob    = (__bf16*)(ws + OFF_AO);
  float*  bias   = (float*)(ws + OFF_BIAS);

  k_prep<<<dim3(8, 8, 36), 256, 0, stream>>>(hs, Wq, Wk, Wv, Wo, rb, hsf, wfb, wo_t, bias);
  k_gemm<0, 16, 512, 512><<<dim3(12, 64), 256, 0, stream>>>(hsf, wfb, qfb, kfb, vtb, nullptr);
  k_attn<<<dim3(256), 512, 0, stream>>>(qfb, kfb, vtb, bias, aob);
  k_gemm<1, 16, 512, 512><<<dim3(4, 64), 256, 0, stream>>>(aob, wo_t, nullptr, nullptr, nullptr, (float*)d_out);
}

// Round 23
// 88.174 us; speedup vs baseline: 1.3958x; 1.0206x over previous
//
#include <hip/hip_runtime.h>
#include <stdint.h>

typedef __attribute__((ext_vector_type(8))) __bf16 bf16x8;
typedef __attribute__((ext_vector_type(4))) __bf16 bf16x4;
typedef __attribute__((ext_vector_type(8))) _Float16 f16x8;
typedef __attribute__((ext_vector_type(4))) float f32x4;
typedef __attribute__((ext_vector_type(4))) unsigned int u32x4;

#define SEQ 2048
#define LOG2E 1.4426950408889634f

// ---------- ws layout (bytes) ----------
#define OFF_AO    0ull               // bf16 [8192][512] (attn out)
#define OFF_WF    8388608ull         // fp16 [1536][512] (transposed QKV weights; Wq pre-scaled log2e)
#define OFF_WO    9961472ull         // bf16 [512][512]
#define OFF_Q     10485760ull        // fp16 [32][2048][64]
#define OFF_K     18874368ull        // fp16 [32][2048][64]
#define OFF_VT    27262976ull        // bf16 [32][64][2048] (s-permuted)
#define OFF_BIAS  35651584ull        // f32 [8][4096] (log2e-scaled)

__device__ __forceinline__ int swz(int row) { return ((row & 7) << 4) ^ ((row & 8) << 1); }

__device__ __forceinline__ void gl_lds16(const void* g, void* l) {
  __builtin_amdgcn_global_load_lds(
      (__attribute__((address_space(1))) void*)(uintptr_t)g,
      (__attribute__((address_space(3))) void*)(uint32_t)(uintptr_t)l, 16, 0, 0);
}

__device__ __forceinline__ float fast_exp2(float x) { return __builtin_amdgcn_exp2f(x); }

// ---------- prep: QKV weights fp16 (z<3) / Wo + bias table (z==3) ----------
__global__ void k_prep(const float* __restrict__ Wq, const float* __restrict__ Wk,
                       const float* __restrict__ Wv, const float* __restrict__ Wo,
                       const float* __restrict__ rel_bias,
                       _Float16* __restrict__ wf, __bf16* __restrict__ wo_t,
                       float* __restrict__ bias_tab) {
  int z = blockIdx.z;
  __shared__ float tile[64][65];
  const float* W = (z == 0) ? Wq : (z == 1) ? Wk : (z == 2) ? Wv : Wo;
  int k0 = blockIdx.y * 64, n0 = blockIdx.x * 64;
  int tx = threadIdx.x & 63, ty = threadIdx.x >> 6;
  for (int r = ty; r < 64; r += 4) tile[r][tx] = W[(size_t)(k0 + r) * 512 + n0 + tx];
  __syncthreads();
  if (z < 3) {
    float scale = (z == 0) ? LOG2E : 1.0f;
    for (int r = ty; r < 64; r += 4)
      wf[(size_t)(z * 512 + n0 + r) * 512 + k0 + tx] = (_Float16)(tile[tx][r] * scale);
  } else {
    for (int r = ty; r < 64; r += 4)
      wo_t[(size_t)(n0 + r) * 512 + k0 + tx] = (__bf16)tile[tx][r];
    int blk = blockIdx.y * 8 + blockIdx.x;
#pragma unroll
    for (int e = 0; e < 2; ++e) {
      int idx = blk * 512 + e * 256 + threadIdx.x;
      int h = idx >> 12, dIdx = idx & 4095;
      float v = 0.f;
      if (dIdx < 4095) {
        int d = dIdx - 2047;
        int rp = d < 0 ? -d : d;
        int bp;
        if (rp < 8) bp = rp;
        else bp = 8 + (rp >= 12) + (rp >= 16) + (rp >= 23) + (rp >= 32) + (rp >= 46) + (rp >= 64) + (rp >= 91);
        v = rel_bias[((d > 0 ? 16 : 0) + bp) * 8 + h] * LOG2E;
      }
      bias_tab[idx] = v;
    }
  }
}

// ---------- GEMM; MODE 0: fused f32->fp16 A-staging QKV; MODE 1: bf16 O-proj ----------
template <int MODE, int KSTEPS, int LDA, int LDB>
__global__ __launch_bounds__(256) void k_gemm(const void* __restrict__ Ap,
                                              const void* __restrict__ Btp,
                                              _Float16* __restrict__ qf,
                                              _Float16* __restrict__ kf,
                                              __bf16* __restrict__ vt,
                                              float* __restrict__ fo) {
  __shared__ __align__(16) char As[2][128 * 32 * 2];
  __shared__ __align__(16) char Bs[2][128 * 32 * 2];
  int tid = threadIdx.x, w = tid >> 6, l = tid & 63;
  int lr = l & 15, lh = l >> 4;
  int nwg = gridDim.x * gridDim.y;
  int flat = blockIdx.y * gridDim.x + blockIdx.x;
  int flat2 = (flat & 7) * (nwg >> 3) + (flat >> 3);
  int m0 = (flat2 / gridDim.x) * 128, n0 = (flat2 % gridDim.x) * 128;
  int wm = (w >> 1) * 64, wn = (w & 1) * 64;
  f32x4 zero4 = {0.f, 0.f, 0.f, 0.f};
  f32x4 acc[4][4];
#pragma unroll
  for (int i = 0; i < 4; ++i)
#pragma unroll
    for (int j = 0; j < 4; ++j) acc[i][j] = zero4;

  auto stage = [&](int kt, int buf) {
    if (MODE == 0) {
      const float* Af = (const float*)Ap;
#pragma unroll
      for (int c = 0; c < 2; ++c) {
        int i = c * 256 + tid;
        int row = i >> 2, cc = i & 3;
        const float* src = Af + (size_t)(m0 + row) * LDA + kt * 32 + cc * 8;
        float4 a = *(const float4*)src, b2 = *(const float4*)(src + 4);
        f16x8 hv;
        hv[0] = (_Float16)a.x;  hv[1] = (_Float16)a.y;
        hv[2] = (_Float16)a.z;  hv[3] = (_Float16)a.w;
        hv[4] = (_Float16)b2.x; hv[5] = (_Float16)b2.y;
        hv[6] = (_Float16)b2.z; hv[7] = (_Float16)b2.w;
        *(f16x8*)&As[buf][i * 16] = hv;
      }
#pragma unroll
      for (int c = 0; c < 2; ++c) {
        int i = c * 256 + tid;
        int row = i >> 2, cc = i & 3;
        gl_lds16((const char*)Btp + ((size_t)(n0 + row) * LDB + kt * 32 + cc * 8) * 2,
                 &Bs[buf][i * 16]);
      }
    } else {
#pragma unroll
      for (int c = 0; c < 2; ++c) {
        int i = c * 256 + tid;
        int row = i >> 2, cc = i & 3;
        gl_lds16((const char*)Ap + ((size_t)(m0 + row) * LDA + kt * 32 + cc * 8) * 2,
                 &As[buf][i * 16]);
        gl_lds16((const char*)Btp + ((size_t)(n0 + row) * LDB + kt * 32 + cc * 8) * 2,
                 &Bs[buf][i * 16]);
      }
    }
  };

  stage(0, 0);
  __syncthreads();
#pragma unroll 2
  for (int kt = 0; kt < KSTEPS; ++kt) {
    int cur = kt & 1;
    if (kt + 1 < KSTEPS) stage(kt + 1, cur ^ 1);
    u32x4 af[4], bfr[4];
#pragma unroll
    for (int mi = 0; mi < 4; ++mi)
      af[mi] = *(const u32x4*)&As[cur][((wm + mi * 16 + lr) * 32 + lh * 8) * 2];
#pragma unroll
    for (int ni = 0; ni < 4; ++ni)
      bfr[ni] = *(const u32x4*)&Bs[cur][((wn + ni * 16 + lr) * 32 + lh * 8) * 2];
#pragma unroll
    for (int mi = 0; mi < 4; ++mi)
#pragma unroll
      for (int ni = 0; ni < 4; ++ni) {
        if (MODE == 0)
          acc[mi][ni] = __builtin_amdgcn_mfma_f32_16x16x32_f16(
              __builtin_bit_cast(f16x8, af[mi]), __builtin_bit_cast(f16x8, bfr[ni]),
              acc[mi][ni], 0, 0, 0);
        else
          acc[mi][ni] = __builtin_amdgcn_mfma_f32_16x16x32_bf16(
              __builtin_bit_cast(bf16x8, af[mi]), __builtin_bit_cast(bf16x8, bfr[ni]),
              acc[mi][ni], 0, 0, 0);
      }
    __syncthreads();
  }

  if (MODE == 0 && n0 >= 1024) {
#pragma unroll
    for (int mi = 0; mi < 4; ++mi)
#pragma unroll
      for (int ni = 0; ni < 4; ++ni) {
        int m = m0 + wm + mi * 16 + lh * 4;
        int n = n0 + wn + ni * 16 + lr;
        int c9 = n & 511, hh = c9 >> 6, dh = c9 & 63;
        int b = m >> 11, s = m & 2047;
        int loc = s & 63;
        int pp = ((loc >> 5) << 5) | (((loc >> 2) & 3) << 3) | (((loc >> 4) & 1) << 2);
        bf16x4 o;
#pragma unroll
        for (int r = 0; r < 4; ++r) o[r] = (__bf16)acc[mi][ni][r];
        *(bf16x4*)&vt[((size_t)(b * 8 + hh) * 64 + dh) * 2048 + (s & ~63) + pp] = o;
      }
    return;
  }

#pragma unroll
  for (int mi = 0; mi < 4; ++mi)
#pragma unroll
    for (int ni = 0; ni < 4; ++ni)
#pragma unroll
      for (int r = 0; r < 4; ++r) {
        int m = m0 + wm + mi * 16 + lh * 4 + r;
        int n = n0 + wn + ni * 16 + lr;
        float vv = acc[mi][ni][r];
        if (MODE == 0) {
          int which = n >> 9, c9 = n & 511, hh = c9 >> 6, dh = c9 & 63;
          int b = m >> 11, s = m & 2047;
          size_t o = (size_t)((b * 8 + hh) * 2048 + s) * 64 + dh;
          if (which == 0) qf[o] = (_Float16)vv;
          else            kf[o] = (_Float16)vv;
        } else {
          fo[(size_t)m * 512 + n] = vv;
        }
      }
}

// ---------- flash attention: fp16 QK, QBLK=256, 6-buffer cross-kt software pipeline ----------
__global__ __launch_bounds__(512) void k_attn(const _Float16* __restrict__ qfp,
                                              const _Float16* __restrict__ kfp,
                                              const __bf16* __restrict__ vt,
                                              const float* __restrict__ bias_tab,
                                              __bf16* __restrict__ ao) {
  __shared__ __align__(16) char Ks[6][64 * 128];   // fp16 rows
  __shared__ __align__(16) char Vs[6][64 * 128];   // bf16 rows
  __shared__ float bias_s[2304];
  int tid = threadIdx.x, w = tid >> 6, l = tid & 63;
  int lr = l & 15, lh = l >> 4;
  int d = blockIdx.x;                              // 256 blocks (1/CU)
  int bh = (d & 7) + ((d >> 3) & 3) * 8;
  int q0 = (d >> 5) * 256;
  int h = bh & 7, b = bh >> 3;
  const char* kbase = (const char*)(kfp + (size_t)bh * SEQ * 64);
  const char* vbase = (const char*)(vt + (size_t)bh * 64 * SEQ);

  float bR = bias_tab[h * 4096 + 2047 + 200];
  float bL = bias_tab[h * 4096 + 2047 - 200];

  for (int j = tid; j < 2304; j += 512)
    bias_s[j] = bias_tab[h * 4096 + (1792 - q0) + j];

  auto stageKV = [&](int kt, int buf) {
    const char* kb = kbase + (size_t)kt * 64 * 128;
    const char* vb = vbase + (size_t)kt * 128;
    int row = tid >> 3, colb = (tid & 7) * 16;
    gl_lds16(kb + row * 128 + (colb ^ swz(row)), &Ks[buf][tid * 16]);
    gl_lds16(vb + (size_t)row * 4096 + (colb ^ swz(row)), &Vs[buf][tid * 16]);
  };

  // Q fragments (fp16, 2 q-sets of 16 rows) straight from global
  f16x8 qf[2][2];
#pragma unroll
  for (int qs = 0; qs < 2; ++qs) {
    int qrow = w * 32 + qs * 16 + lr;
    const _Float16* qg = qfp + ((size_t)bh * SEQ + q0 + qrow) * 64;
    qf[qs][0] = *(const f16x8*)(qg + lh * 8);
    qf[qs][1] = *(const f16x8*)(qg + 32 + lh * 8);
  }

  float l_run0 = 0.f, l_run1 = 0.f;
  f32x4 zero4 = {0.f, 0.f, 0.f, 0.f};
  f32x4 oacc[2][4];
#pragma unroll
  for (int qs = 0; qs < 2; ++qs)
#pragma unroll
    for (int i = 0; i < 4; ++i) oacc[qs][i] = zero4;

  // QK phase: bias C-init + 16 fp16 MFMAs into sacc (consumed by finish, possibly next iter)
  auto qk = [&](int kt, int buf, f32x4 (&sacc)[2][4]) {
    int dmin = kt * 64 - q0 - 255, dmax = kt * 64 + 63 - q0;
    bool far = (dmin >= 91) || (dmax <= -91);
    f32x4 cinit[2][4];
    if (far) {
      float cb = (dmin >= 91) ? bR : bL;
#pragma unroll
      for (int qs = 0; qs < 2; ++qs)
#pragma unroll
        for (int t = 0; t < 4; ++t)
#pragma unroll
          for (int r = 0; r < 4; ++r) cinit[qs][t][r] = cb;
    } else {
#pragma unroll
      for (int qs = 0; qs < 2; ++qs) {
        int jb = kt * 64 + lh * 4 + 255 - (w * 32 + qs * 16 + lr);
#pragma unroll
        for (int t = 0; t < 4; ++t)
#pragma unroll
          for (int r = 0; r < 4; ++r) cinit[qs][t][r] = bias_s[jb + t * 16 + r];
      }
    }
    const char* kb = &Ks[buf][0];
    __builtin_amdgcn_s_setprio(1);
#pragma unroll
    for (int t = 0; t < 4; ++t) {
      int row = t * 16 + lr;
      f16x8 b0 = *(const f16x8*)(kb + row * 128 + ((lh * 16) ^ swz(row)));
      f16x8 b1 = *(const f16x8*)(kb + row * 128 + ((64 + lh * 16) ^ swz(row)));
#pragma unroll
      for (int qs = 0; qs < 2; ++qs) {
        f32x4 z = cinit[qs][t];
        z = __builtin_amdgcn_mfma_f32_16x16x32_f16(b0, qf[qs][0], z, 0, 0, 0);
        z = __builtin_amdgcn_mfma_f32_16x16x32_f16(b1, qf[qs][1], z, 0, 0, 0);
        sacc[qs][t] = z;
      }
    }
    __builtin_amdgcn_s_setprio(0);
  };

  // finish phase: static-shift softmax + bf16 PV
  auto finish = [&](int buf, f32x4 (&sacc)[2][4]) {
    bf16x8 paA[2], paB[2];
#pragma unroll
    for (int qs = 0; qs < 2; ++qs) {
      float p[4][4];
      float rt[4];
#pragma unroll
      for (int t = 0; t < 4; ++t) {
#pragma unroll
        for (int r = 0; r < 4; ++r) p[t][r] = fast_exp2(sacc[qs][t][r]);
        rt[t] = (p[t][0] + p[t][1]) + (p[t][2] + p[t][3]);
      }
      if (qs == 0) l_run0 += (rt[0] + rt[1]) + (rt[2] + rt[3]);
      else         l_run1 += (rt[0] + rt[1]) + (rt[2] + rt[3]);
      uint32_t pk[4][2];
#pragma unroll
      for (int t = 0; t < 4; ++t) {
        asm("v_cvt_pk_bf16_f32 %0, %1, %2" : "=v"(pk[t][0]) : "v"(p[t][0]), "v"(p[t][1]));
        asm("v_cvt_pk_bf16_f32 %0, %1, %2" : "=v"(pk[t][1]) : "v"(p[t][2]), "v"(p[t][3]));
      }
      u32x4 A0 = {pk[0][0], pk[0][1], pk[1][0], pk[1][1]};
      u32x4 A1 = {pk[2][0], pk[2][1], pk[3][0], pk[3][1]};
      paA[qs] = __builtin_bit_cast(bf16x8, A0);
      paB[qs] = __builtin_bit_cast(bf16x8, A1);
    }
    const char* vbr = &Vs[buf][0];
    __builtin_amdgcn_s_setprio(1);
#pragma unroll
    for (int ni = 0; ni < 4; ++ni) {
      int vrow = ni * 16 + lr;
      bf16x8 v0 = *(const bf16x8*)(vbr + vrow * 128 + ((lh * 16) ^ swz(vrow)));
      bf16x8 v1 = *(const bf16x8*)(vbr + vrow * 128 + ((64 + lh * 16) ^ swz(vrow)));
#pragma unroll
      for (int qs = 0; qs < 2; ++qs) {
        oacc[qs][ni] = __builtin_amdgcn_mfma_f32_16x16x32_bf16(paA[qs], v0, oacc[qs][ni], 0, 0, 0);
        oacc[qs][ni] = __builtin_amdgcn_mfma_f32_16x16x32_bf16(paB[qs], v1, oacc[qs][ni], 0, 0, 0);
      }
    }
    __builtin_amdgcn_s_setprio(0);
  };

  // 6-buffer (mod-6) pipeline, barrier per 2 kt; finish(2kp-1) is independent of
  // the current qk batches -> softmax VALU fills the QK-MFMA shadow.
  stageKV(0, 0);
  stageKV(1, 1);
  __syncthreads();
  f32x4 sA[2][4], sB0[2][4], sB1[2][4];
#pragma unroll 2
  for (int kp = 0; kp < 16; ++kp) {
    if (kp <= 14) {
      stageKV(2 * kp + 2, (2 * kp + 2) % 6);
      stageKV(2 * kp + 3, (2 * kp + 3) % 6);
    }
    qk(2 * kp, (2 * kp) % 6, sA);
    if (kp & 1) {
      qk(2 * kp + 1, (2 * kp + 1) % 6, sB1);
      if (kp >= 1) finish((2 * kp - 1) % 6, sB0);   // prev iter's odd kt
    } else {
      qk(2 * kp + 1, (2 * kp + 1) % 6, sB0);
      if (kp >= 1) finish((2 * kp - 1) % 6, sB1);
    }
    finish((2 * kp) % 6, sA);
    __syncthreads();
  }
  finish(31 % 6, sB1);                              // kt=31 (written at kp=15, odd)

  // one-time class reduce of per-lane l partials
  l_run0 += __shfl_xor(l_run0, 16);
  l_run0 += __shfl_xor(l_run0, 32);
  l_run1 += __shfl_xor(l_run1, 16);
  l_run1 += __shfl_xor(l_run1, 32);

#pragma unroll
  for (int qs = 0; qs < 2; ++qs) {
    float lsel = (qs == 0) ? l_run0 : l_run1;
#pragma unroll
    for (int r = 0; r < 4; ++r) {
      float linv = 1.0f / __shfl(lsel, lh * 4 + r);
      int s = q0 + w * 32 + qs * 16 + lh * 4 + r;
#pragma unroll
      for (int ni = 0; ni < 4; ++ni) {
        int dh = ni * 16 + lr;
        ao[((size_t)(b * 2048 + s)) * 512 + h * 64 + dh] = (__bf16)(oacc[qs][ni][r] * linv);
      }
    }
  }
}

extern "C" void kernel_launch(void* const* d_in, const int* in_sizes, int n_in,
                              void* d_out, int out_size, void* d_ws, size_t ws_size,
                              hipStream_t stream) {
  (void)in_sizes; (void)n_in; (void)out_size; (void)ws_size;
  const float* hs = (const float*)d_in[0];
  const float* Wq = (const float*)d_in[1];
  const float* Wk = (const float*)d_in[2];
  const float* Wv = (const float*)d_in[3];
  const float* Wo = (const float*)d_in[4];
  const float* rb = (const float*)d_in[5];
  char* ws = (char*)d_ws;
  _Float16* wfb  = (_Float16*)(ws + OFF_WF);
  __bf16* wo_t   = (__bf16*)(ws + OFF_WO);
  _Float16* qfb  = (_Float16*)(ws + OFF_Q);
  _Float16* kfb  = (_Float16*)(ws + OFF_K);
  __bf16* vtb    = (__bf16*)(ws + OFF_VT);
  __bf16* aob    = (__bf16*)(ws + OFF_AO);
  float*  bias   = (float*)(ws + OFF_BIAS);

  k_prep<<<dim3(8, 8, 4), 256, 0, stream>>>(Wq, Wk, Wv, Wo, rb, wfb, wo_t, bias);
  k_gemm<0, 16, 512, 512><<<dim3(12, 64), 256, 0, stream>>>(hs, wfb, qfb, kfb, vtb, nullptr);
  k_attn<<<dim3(256), 512, 0, stream>>>(qfb, kfb, vtb, bias, aob);
  k_gemm<1, 16, 512, 512><<<dim3(4, 64), 256, 0, stream>>>(aob, wo_t, nullptr, nullptr, nullptr, (float*)d_out);
}

// Round 24
// 87.034 us; speedup vs baseline: 1.4141x; 1.0131x over previous
//
#include <hip/hip_runtime.h>
#include <stdint.h>

typedef __attribute__((ext_vector_type(8))) __bf16 bf16x8;
typedef __attribute__((ext_vector_type(4))) __bf16 bf16x4;
typedef __attribute__((ext_vector_type(8))) _Float16 f16x8;
typedef __attribute__((ext_vector_type(4))) float f32x4;
typedef __attribute__((ext_vector_type(4))) unsigned int u32x4;

#define SEQ 2048
#define LOG2E 1.4426950408889634f

// ---------- ws layout (bytes) ----------
#define OFF_AO    0ull               // bf16 [8192][512] (attn out)
#define OFF_WF    8388608ull         // fp16 [1536][512] (transposed QKV weights; Wq pre-scaled log2e)
#define OFF_WO    9961472ull         // bf16 [512][512]
#define OFF_Q     10485760ull        // fp16 [32][2048][64]
#define OFF_K     18874368ull        // fp16 [32][2048][64]
#define OFF_VT    27262976ull        // bf16 [32][64][2048] (s-permuted)
#define OFF_BIAS  35651584ull        // f32 [8][4096] (log2e-scaled)

__device__ __forceinline__ int swz(int row) { return ((row & 7) << 4) ^ ((row & 8) << 1); }

__device__ __forceinline__ void gl_lds16(const void* g, void* l) {
  __builtin_amdgcn_global_load_lds(
      (__attribute__((address_space(1))) void*)(uintptr_t)g,
      (__attribute__((address_space(3))) void*)(uint32_t)(uintptr_t)l, 16, 0, 0);
}

__device__ __forceinline__ float fast_exp2(float x) { return __builtin_amdgcn_exp2f(x); }

// ---------- prep: QKV weights fp16 (z<3) / Wo + bias table (z==3) ----------
__global__ void k_prep(const float* __restrict__ Wq, const float* __restrict__ Wk,
                       const float* __restrict__ Wv, const float* __restrict__ Wo,
                       const float* __restrict__ rel_bias,
                       _Float16* __restrict__ wf, __bf16* __restrict__ wo_t,
                       float* __restrict__ bias_tab) {
  int z = blockIdx.z;
  __shared__ float tile[64][65];
  const float* W = (z == 0) ? Wq : (z == 1) ? Wk : (z == 2) ? Wv : Wo;
  int k0 = blockIdx.y * 64, n0 = blockIdx.x * 64;
  int tx = threadIdx.x & 63, ty = threadIdx.x >> 6;
  for (int r = ty; r < 64; r += 4) tile[r][tx] = W[(size_t)(k0 + r) * 512 + n0 + tx];
  __syncthreads();
  if (z < 3) {
    float scale = (z == 0) ? LOG2E : 1.0f;
    for (int r = ty; r < 64; r += 4)
      wf[(size_t)(z * 512 + n0 + r) * 512 + k0 + tx] = (_Float16)(tile[tx][r] * scale);
  } else {
    for (int r = ty; r < 64; r += 4)
      wo_t[(size_t)(n0 + r) * 512 + k0 + tx] = (__bf16)tile[tx][r];
    int blk = blockIdx.y * 8 + blockIdx.x;
#pragma unroll
    for (int e = 0; e < 2; ++e) {
      int idx = blk * 512 + e * 256 + threadIdx.x;
      int h = idx >> 12, dIdx = idx & 4095;
      float v = 0.f;
      if (dIdx < 4095) {
        int d = dIdx - 2047;
        int rp = d < 0 ? -d : d;
        int bp;
        if (rp < 8) bp = rp;
        else bp = 8 + (rp >= 12) + (rp >= 16) + (rp >= 23) + (rp >= 32) + (rp >= 46) + (rp >= 64) + (rp >= 91);
        v = rel_bias[((d > 0 ? 16 : 0) + bp) * 8 + h] * LOG2E;
      }
      bias_tab[idx] = v;
    }
  }
}

// ---------- GEMM; MODE 0: fused f32->fp16 A-staging QKV; MODE 1: bf16 O-proj ----------
template <int MODE, int KSTEPS, int LDA, int LDB>
__global__ __launch_bounds__(256) void k_gemm(const void* __restrict__ Ap,
                                              const void* __restrict__ Btp,
                                              _Float16* __restrict__ qf,
                                              _Float16* __restrict__ kf,
                                              __bf16* __restrict__ vt,
                                              float* __restrict__ fo) {
  __shared__ __align__(16) char As[2][128 * 32 * 2];
  __shared__ __align__(16) char Bs[2][128 * 32 * 2];
  int tid = threadIdx.x, w = tid >> 6, l = tid & 63;
  int lr = l & 15, lh = l >> 4;
  int nwg = gridDim.x * gridDim.y;
  int flat = blockIdx.y * gridDim.x + blockIdx.x;
  int flat2 = (flat & 7) * (nwg >> 3) + (flat >> 3);
  int m0 = (flat2 / gridDim.x) * 128, n0 = (flat2 % gridDim.x) * 128;
  int wm = (w >> 1) * 64, wn = (w & 1) * 64;
  f32x4 zero4 = {0.f, 0.f, 0.f, 0.f};
  f32x4 acc[4][4];
#pragma unroll
  for (int i = 0; i < 4; ++i)
#pragma unroll
    for (int j = 0; j < 4; ++j) acc[i][j] = zero4;

  auto stage = [&](int kt, int buf) {
    if (MODE == 0) {
      const float* Af = (const float*)Ap;
#pragma unroll
      for (int c = 0; c < 2; ++c) {
        int i = c * 256 + tid;
        int row = i >> 2, cc = i & 3;
        const float* src = Af + (size_t)(m0 + row) * LDA + kt * 32 + cc * 8;
        float4 a = *(const float4*)src, b2 = *(const float4*)(src + 4);
        f16x8 hv;
        hv[0] = (_Float16)a.x;  hv[1] = (_Float16)a.y;
        hv[2] = (_Float16)a.z;  hv[3] = (_Float16)a.w;
        hv[4] = (_Float16)b2.x; hv[5] = (_Float16)b2.y;
        hv[6] = (_Float16)b2.z; hv[7] = (_Float16)b2.w;
        *(f16x8*)&As[buf][i * 16] = hv;
      }
#pragma unroll
      for (int c = 0; c < 2; ++c) {
        int i = c * 256 + tid;
        int row = i >> 2, cc = i & 3;
        gl_lds16((const char*)Btp + ((size_t)(n0 + row) * LDB + kt * 32 + cc * 8) * 2,
                 &Bs[buf][i * 16]);
      }
    } else {
#pragma unroll
      for (int c = 0; c < 2; ++c) {
        int i = c * 256 + tid;
        int row = i >> 2, cc = i & 3;
        gl_lds16((const char*)Ap + ((size_t)(m0 + row) * LDA + kt * 32 + cc * 8) * 2,
                 &As[buf][i * 16]);
        gl_lds16((const char*)Btp + ((size_t)(n0 + row) * LDB + kt * 32 + cc * 8) * 2,
                 &Bs[buf][i * 16]);
      }
    }
  };

  stage(0, 0);
  __syncthreads();
#pragma unroll 2
  for (int kt = 0; kt < KSTEPS; ++kt) {
    int cur = kt & 1;
    if (kt + 1 < KSTEPS) stage(kt + 1, cur ^ 1);
    u32x4 af[4], bfr[4];
#pragma unroll
    for (int mi = 0; mi < 4; ++mi)
      af[mi] = *(const u32x4*)&As[cur][((wm + mi * 16 + lr) * 32 + lh * 8) * 2];
#pragma unroll
    for (int ni = 0; ni < 4; ++ni)
      bfr[ni] = *(const u32x4*)&Bs[cur][((wn + ni * 16 + lr) * 32 + lh * 8) * 2];
#pragma unroll
    for (int mi = 0; mi < 4; ++mi)
#pragma unroll
      for (int ni = 0; ni < 4; ++ni) {
        if (MODE == 0)
          acc[mi][ni] = __builtin_amdgcn_mfma_f32_16x16x32_f16(
              __builtin_bit_cast(f16x8, af[mi]), __builtin_bit_cast(f16x8, bfr[ni]),
              acc[mi][ni], 0, 0, 0);
        else
          acc[mi][ni] = __builtin_amdgcn_mfma_f32_16x16x32_bf16(
              __builtin_bit_cast(bf16x8, af[mi]), __builtin_bit_cast(bf16x8, bfr[ni]),
              acc[mi][ni], 0, 0, 0);
      }
    __syncthreads();
  }

  if (MODE == 0 && n0 >= 1024) {
#pragma unroll
    for (int mi = 0; mi < 4; ++mi)
#pragma unroll
      for (int ni = 0; ni < 4; ++ni) {
        int m = m0 + wm + mi * 16 + lh * 4;
        int n = n0 + wn + ni * 16 + lr;
        int c9 = n & 511, hh = c9 >> 6, dh = c9 & 63;
        int b = m >> 11, s = m & 2047;
        int loc = s & 63;
        int pp = ((loc >> 5) << 5) | (((loc >> 2) & 3) << 3) | (((loc >> 4) & 1) << 2);
        bf16x4 o;
#pragma unroll
        for (int r = 0; r < 4; ++r) o[r] = (__bf16)acc[mi][ni][r];
        *(bf16x4*)&vt[((size_t)(b * 8 + hh) * 64 + dh) * 2048 + (s & ~63) + pp] = o;
      }
    return;
  }

#pragma unroll
  for (int mi = 0; mi < 4; ++mi)
#pragma unroll
    for (int ni = 0; ni < 4; ++ni)
#pragma unroll
      for (int r = 0; r < 4; ++r) {
        int m = m0 + wm + mi * 16 + lh * 4 + r;
        int n = n0 + wn + ni * 16 + lr;
        float vv = acc[mi][ni][r];
        if (MODE == 0) {
          int which = n >> 9, c9 = n & 511, hh = c9 >> 6, dh = c9 & 63;
          int b = m >> 11, s = m & 2047;
          size_t o = (size_t)((b * 8 + hh) * 2048 + s) * 64 + dh;
          if (which == 0) qf[o] = (_Float16)vv;
          else            kf[o] = (_Float16)vv;
        } else {
          fo[(size_t)m * 512 + n] = vv;
        }
      }
}

// ---------- flash attention: fp16 QK single-pass, QBLK=256, static-shift exp, 4-buffer ----------
__global__ __launch_bounds__(512) void k_attn(const _Float16* __restrict__ qfp,
                                              const _Float16* __restrict__ kfp,
                                              const __bf16* __restrict__ vt,
                                              const float* __restrict__ bias_tab,
                                              __bf16* __restrict__ ao) {
  __shared__ __align__(16) char Ks[4][64 * 128];   // fp16 rows (64 elem * 2B)
  __shared__ __align__(16) char Vs[4][64 * 128];   // bf16 rows
  __shared__ float bias_s[2304];
  int tid = threadIdx.x, w = tid >> 6, l = tid & 63;
  int lr = l & 15, lh = l >> 4;
  int d = blockIdx.x;                              // 256 blocks (1/CU)
  int bh = (d & 7) + ((d >> 3) & 3) * 8;
  int q0 = (d >> 5) * 256;
  int h = bh & 7, b = bh >> 3;
  const char* kbase = (const char*)(kfp + (size_t)bh * SEQ * 64);
  const char* vbase = (const char*)(vt + (size_t)bh * 64 * SEQ);

  float bR = bias_tab[h * 4096 + 2047 + 200];
  float bL = bias_tab[h * 4096 + 2047 - 200];

  for (int j = tid; j < 2304; j += 512)
    bias_s[j] = bias_tab[h * 4096 + (1792 - q0) + j];

  auto stageKV = [&](int kt, int buf) {
    const char* kb = kbase + (size_t)kt * 64 * 128;
    const char* vb = vbase + (size_t)kt * 128;
    int row = tid >> 3, colb = (tid & 7) * 16;
    gl_lds16(kb + row * 128 + (colb ^ swz(row)), &Ks[buf][tid * 16]);
    gl_lds16(vb + (size_t)row * 4096 + (colb ^ swz(row)), &Vs[buf][tid * 16]);
  };

  // Q fragments (fp16, 2 q-sets of 16 rows) straight from global
  f16x8 qf[2][2];
#pragma unroll
  for (int qs = 0; qs < 2; ++qs) {
    int qrow = w * 32 + qs * 16 + lr;
    const _Float16* qg = qfp + ((size_t)bh * SEQ + q0 + qrow) * 64;
    qf[qs][0] = *(const f16x8*)(qg + lh * 8);
    qf[qs][1] = *(const f16x8*)(qg + 32 + lh * 8);
  }

  float l_run0 = 0.f, l_run1 = 0.f;
  f32x4 zero4 = {0.f, 0.f, 0.f, 0.f};
  f32x4 oacc[2][4];
#pragma unroll
  for (int qs = 0; qs < 2; ++qs)
#pragma unroll
    for (int i = 0; i < 4; ++i) oacc[qs][i] = zero4;

  // QK phase: bias C-init + 16 fp16 MFMAs into sacc
  auto qk = [&](int kt, int buf, f32x4 (&sacc)[2][4]) {
    int dmin = kt * 64 - q0 - 255, dmax = kt * 64 + 63 - q0;
    bool far = (dmin >= 91) || (dmax <= -91);
    f32x4 cinit[2][4];
    if (far) {
      float cb = (dmin >= 91) ? bR : bL;
#pragma unroll
      for (int qs = 0; qs < 2; ++qs)
#pragma unroll
        for (int t = 0; t < 4; ++t)
#pragma unroll
          for (int r = 0; r < 4; ++r) cinit[qs][t][r] = cb;
    } else {
#pragma unroll
      for (int qs = 0; qs < 2; ++qs) {
        int jb = kt * 64 + lh * 4 + 255 - (w * 32 + qs * 16 + lr);
#pragma unroll
        for (int t = 0; t < 4; ++t)
#pragma unroll
          for (int r = 0; r < 4; ++r) cinit[qs][t][r] = bias_s[jb + t * 16 + r];
      }
    }
    const char* kb = &Ks[buf][0];
    __builtin_amdgcn_s_setprio(1);
#pragma unroll
    for (int t = 0; t < 4; ++t) {
      int row = t * 16 + lr;
      f16x8 b0 = *(const f16x8*)(kb + row * 128 + ((lh * 16) ^ swz(row)));
      f16x8 b1 = *(const f16x8*)(kb + row * 128 + ((64 + lh * 16) ^ swz(row)));
#pragma unroll
      for (int qs = 0; qs < 2; ++qs) {
        f32x4 z = cinit[qs][t];
        z = __builtin_amdgcn_mfma_f32_16x16x32_f16(b0, qf[qs][0], z, 0, 0, 0);
        z = __builtin_amdgcn_mfma_f32_16x16x32_f16(b1, qf[qs][1], z, 0, 0, 0);
        sacc[qs][t] = z;
      }
    }
    __builtin_amdgcn_s_setprio(0);
  };

  // finish phase: static-shift softmax + bf16 PV
  auto finish = [&](int buf, f32x4 (&sacc)[2][4]) {
    bf16x8 paA[2], paB[2];
#pragma unroll
    for (int qs = 0; qs < 2; ++qs) {
      float p[4][4];
      float rt[4];
#pragma unroll
      for (int t = 0; t < 4; ++t) {
#pragma unroll
        for (int r = 0; r < 4; ++r) p[t][r] = fast_exp2(sacc[qs][t][r]);
        rt[t] = (p[t][0] + p[t][1]) + (p[t][2] + p[t][3]);
      }
      if (qs == 0) l_run0 += (rt[0] + rt[1]) + (rt[2] + rt[3]);
      else         l_run1 += (rt[0] + rt[1]) + (rt[2] + rt[3]);
      uint32_t pk[4][2];
#pragma unroll
      for (int t = 0; t < 4; ++t) {
        asm("v_cvt_pk_bf16_f32 %0, %1, %2" : "=v"(pk[t][0]) : "v"(p[t][0]), "v"(p[t][1]));
        asm("v_cvt_pk_bf16_f32 %0, %1, %2" : "=v"(pk[t][1]) : "v"(p[t][2]), "v"(p[t][3]));
      }
      u32x4 A0 = {pk[0][0], pk[0][1], pk[1][0], pk[1][1]};
      u32x4 A1 = {pk[2][0], pk[2][1], pk[3][0], pk[3][1]};
      paA[qs] = __builtin_bit_cast(bf16x8, A0);
      paB[qs] = __builtin_bit_cast(bf16x8, A1);
    }
    const char* vbr = &Vs[buf][0];
    __builtin_amdgcn_s_setprio(1);
#pragma unroll
    for (int ni = 0; ni < 4; ++ni) {
      int vrow = ni * 16 + lr;
      bf16x8 v0 = *(const bf16x8*)(vbr + vrow * 128 + ((lh * 16) ^ swz(vrow)));
      bf16x8 v1 = *(const bf16x8*)(vbr + vrow * 128 + ((64 + lh * 16) ^ swz(vrow)));
#pragma unroll
      for (int qs = 0; qs < 2; ++qs) {
        oacc[qs][ni] = __builtin_amdgcn_mfma_f32_16x16x32_bf16(paA[qs], v0, oacc[qs][ni], 0, 0, 0);
        oacc[qs][ni] = __builtin_amdgcn_mfma_f32_16x16x32_bf16(paB[qs], v1, oacc[qs][ni], 0, 0, 0);
      }
    }
    __builtin_amdgcn_s_setprio(0);
  };

  // 4-buffer pipeline, one barrier per 2 kt; QK batches issued ahead of finishes
  stageKV(0, 0);
  stageKV(1, 1);
  __syncthreads();
  f32x4 sA[2][4], sB[2][4];
#pragma unroll 2
  for (int kp = 0; kp < 16; ++kp) {
    int rb_ = (kp & 1) * 2;
    qk(2 * kp, rb_, sA);
    qk(2 * kp + 1, rb_ + 1, sB);
    if (kp < 15) {
      stageKV(2 * kp + 2, rb_ ^ 2);
      stageKV(2 * kp + 3, (rb_ ^ 2) + 1);
    }
    finish(rb_, sA);
    finish(rb_ + 1, sB);
    __syncthreads();
  }

  // one-time class reduce of per-lane l partials
  l_run0 += __shfl_xor(l_run0, 16);
  l_run0 += __shfl_xor(l_run0, 32);
  l_run1 += __shfl_xor(l_run1, 16);
  l_run1 += __shfl_xor(l_run1, 32);

#pragma unroll
  for (int qs = 0; qs < 2; ++qs) {
    float lsel = (qs == 0) ? l_run0 : l_run1;
#pragma unroll
    for (int r = 0; r < 4; ++r) {
      float linv = 1.0f / __shfl(lsel, lh * 4 + r);
      int s = q0 + w * 32 + qs * 16 + lh * 4 + r;
#pragma unroll
      for (int ni = 0; ni < 4; ++ni) {
        int dh = ni * 16 + lr;
        ao[((size_t)(b * 2048 + s)) * 512 + h * 64 + dh] = (__bf16)(oacc[qs][ni][r] * linv);
      }
    }
  }
}

extern "C" void kernel_launch(void* const* d_in, const int* in_sizes, int n_in,
                              void* d_out, int out_size, void* d_ws, size_t ws_size,
                              hipStream_t stream) {
  (void)in_sizes; (void)n_in; (void)out_size; (void)ws_size;
  const float* hs = (const float*)d_in[0];
  const float* Wq = (const float*)d_in[1];
  const float* Wk = (const float*)d_in[2];
  const float* Wv = (const float*)d_in[3];
  const float* Wo = (const float*)d_in[4];
  const float* rb = (const float*)d_in[5];
  char* ws = (char*)d_ws;
  _Float16* wfb  = (_Float16*)(ws + OFF_WF);
  __bf16* wo_t   = (__bf16*)(ws + OFF_WO);
  _Float16* qfb  = (_Float16*)(ws + OFF_Q);
  _Float16* kfb  = (_Float16*)(ws + OFF_K);
  __bf16* vtb    = (__bf16*)(ws + OFF_VT);
  __bf16* aob    = (__bf16*)(ws + OFF_AO);
  float*  bias   = (float*)(ws + OFF_BIAS);

  k_prep<<<dim3(8, 8, 4), 256, 0, stream>>>(Wq, Wk, Wv, Wo, rb, wfb, wo_t, bias);
  k_gemm<0, 16, 512, 512><<<dim3(12, 64), 256, 0, stream>>>(hs, wfb, qfb, kfb, vtb, nullptr);
  k_attn<<<dim3(256), 512, 0, stream>>>(qfb, kfb, vtb, bias, aob);
  k_gemm<1, 16, 512, 512><<<dim3(4, 64), 256, 0, stream>>>(aob, wo_t, nullptr, nullptr, nullptr, (float*)d_out);
}